// Round 8
// baseline (1068.547 us; speedup 1.0000x reference)
//
#include <hip/hip_runtime.h>

#define F_IN 256
#define HID 16
#define NCLS 8

#define DBSH 12                    // dst-bin = 4096 nodes
#define DBN  4096
#define SSCSH 13                   // src super-chunk = 8192 nodes
#define NB2MAX 336                 // >= ndb(25) * nssc(13)
#define CAP2 12000u                // per (db,ssc) bin capacity (mean ~9850)
#define NCH 416                    // chunk slots per db (13 ssc * 32)
#define TILE 4096
#define S1 6                       // conv1 split (per feature-plane)
#define S2 12                      // conv2 split
#define WINP 16                    // pool window (graphs per 1024-node block)

typedef float f4v __attribute__((ext_vector_type(4)));

// ---------- init per-bin cursors ---------------------------------------------
__global__ void k_bininit(unsigned* __restrict__ binCur, int nb2) {
    int t = blockIdx.x * blockDim.x + threadIdx.x;
    if (t < nb2) binCur[t] = (unsigned)t * CAP2;
}

// ---------- pass A: bin edges by (dst-bin, src-superchunk) -------------------
__global__ void __launch_bounds__(256) k_binA(const int* __restrict__ src,
                                              const int* __restrict__ dst, int e,
                                              int nssc,
                                              unsigned* __restrict__ binCur,
                                              unsigned* __restrict__ binbuf) {
    __shared__ unsigned scnt[NB2MAX], lbase[NB2MAX], gbase[NB2MAX];
    __shared__ unsigned sbuf[TILE];
    __shared__ unsigned short sbin[TILE];
    int t = threadIdx.x;
    for (int i = t; i < NB2MAX; i += 256) scnt[i] = 0u;
    __syncthreads();
    int base = blockIdx.x * TILE;
    unsigned ent[16], rank[16];
    int ebin[16];
#pragma unroll
    for (int i = 0; i < 16; ++i) {
        int j = base + t + i * 256;
        ebin[i] = -1;
        if (j < e) {
            int d = __builtin_nontemporal_load(&dst[j]);
            int s = __builtin_nontemporal_load(&src[j]);
            ent[i] = ((unsigned)s << DBSH) | ((unsigned)d & (DBN - 1));
            ebin[i] = (d >> DBSH) * nssc + (s >> SSCSH);
            rank[i] = atomicAdd(&scnt[ebin[i]], 1u);
        }
    }
    __syncthreads();
    if (t == 0) {
        unsigned run = 0;
        for (int b = 0; b < NB2MAX; ++b) { lbase[b] = run; run += scnt[b]; }
    }
    __syncthreads();
    for (int b = t; b < NB2MAX; b += 256)
        if (scnt[b] > 0u) gbase[b] = atomicAdd(&binCur[b], scnt[b]);
    __syncthreads();
#pragma unroll
    for (int i = 0; i < 16; ++i)
        if (ebin[i] >= 0) {
            unsigned p = lbase[ebin[i]] + rank[i];
            sbuf[p] = ent[i];
            sbin[p] = (unsigned short)ebin[i];
        }
    __syncthreads();
    int total = e - base; if (total > TILE) total = TILE;
    for (int idx = t; idx < total; idx += 256) {
        int b = sbin[idx];
        __builtin_nontemporal_store(sbuf[idx], &binbuf[gbase[b] + ((unsigned)idx - lbase[b])]);
    }
}

// ---------- pass B: sort each (db,ssc) slice by 256-node src-chunk -----------
// Also computes in-degree via LDS histogram (no global per-edge atomics).
__global__ void __launch_bounds__(256) k_binB(const unsigned* __restrict__ binbuf,
                                              const unsigned* __restrict__ binCur,
                                              int nssc, int n,
                                              unsigned* __restrict__ out2,
                                              unsigned* __restrict__ offA,
                                              unsigned* __restrict__ cntA,
                                              unsigned* __restrict__ degc) {
    __shared__ unsigned ccnt[32], coff[33];
    __shared__ unsigned dhist[DBN];
    int t = threadIdx.x;
    int b2 = blockIdx.x;
    int db = b2 / nssc, ssc = b2 % nssc;
    unsigned base = (unsigned)b2 * CAP2;
    unsigned end = binCur[b2];
    if (t < 32) ccnt[t] = 0u;
    for (int i = t; i < DBN; i += 256) dhist[i] = 0u;
    __syncthreads();
    // pass 1: count per chunk + degree histogram
    for (unsigned j = base + t; j < end; j += 256) {
        unsigned e1 = binbuf[j];
        unsigned s = e1 >> DBSH;
        atomicAdd(&ccnt[(s >> 8) & 31], 1u);
        atomicAdd(&dhist[e1 & (DBN - 1)], 1u);
    }
    __syncthreads();
    if (t == 0) {
        unsigned run = 0;
        for (int c = 0; c < 32; ++c) { coff[c] = run; run += ccnt[c]; }
        coff[32] = run;
    }
    __syncthreads();
    if (t < 32) {
        int cg = ssc * 32 + t;
        offA[db * NCH + cg] = base + coff[t];
        cntA[db * NCH + cg] = coff[t + 1] - coff[t];
        ccnt[t] = 0u;  // reuse as rank counters
    }
    __syncthreads();
    // pass 2: permute within slice (scatter confined to ~48KB -> L2-local)
    for (unsigned j = base + t; j < end; j += 256) {
        unsigned e1 = binbuf[j];
        unsigned s = e1 >> DBSH;
        int cl = (s >> 8) & 31;
        unsigned r = atomicAdd(&ccnt[cl], 1u);
        unsigned e2 = ((s & 255u) << DBSH) | (e1 & (DBN - 1));  // (src_local, dst_local)
        out2[base + coff[cl] + r] = e2;
    }
    // flush degree histogram
    __syncthreads();
    int dbase = db << DBSH;
    for (int i = t; i < DBN; i += 256) {
        if (dhist[i] > 0u && dbase + i < n) atomicAdd(&degc[dbase + i], dhist[i]);
    }
}

// ---------- GEMM1: planes t1p[f>>3][n][f&7] = (x @ W1)*rsqrt(deg+1) ----------
__global__ void __launch_bounds__(256) k_gemm1(const float* __restrict__ x,
                                               const float* __restrict__ W1,
                                               const unsigned* __restrict__ degc,
                                               float* __restrict__ t1p, int n) {
    __shared__ float ws[HID][260];
    for (int idx = threadIdx.x; idx < F_IN * HID; idx += 256) {
        int c = idx >> 4, k = idx & 15;
        ws[k][c] = W1[idx];
    }
    __syncthreads();
    int r = blockIdx.x * 16 + (threadIdx.x >> 4);
    int k = threadIdx.x & 15;
    if (r >= n) return;
    const f4v* xr = (const f4v*)(x + (size_t)r * F_IN);
    const f4v* wr = (const f4v*)&ws[k][0];
    float acc = 0.f;
#pragma unroll 8
    for (int c4 = 0; c4 < F_IN / 4; ++c4) {
        f4v v = __builtin_nontemporal_load(&xr[c4]);
        f4v w = wr[c4];
        acc += v[0] * w[0] + v[1] * w[1] + v[2] * w[2] + v[3] * w[3];
    }
    t1p[(size_t)(k >> 3) * n * 8 + (size_t)r * 8 + (k & 7)] =
        acc * rsqrtf((float)(degc[r] + 1u));
}

// ---------- unified aggregation: stream chunk windows into LDS, ds_add acc ---
// block = (dst-bin db, chunk-range split sp); 8-feat plane.
__global__ void __launch_bounds__(512) k_agg(const unsigned* __restrict__ out2,
                                             const unsigned* __restrict__ offA,
                                             const unsigned* __restrict__ cntA,
                                             const float* __restrict__ plane,
                                             float* __restrict__ part,
                                             int n, int nchunks, int S) {
    __shared__ float win[2][256 * 8];   // 16 KB
    __shared__ float acc[DBN * 8];      // 128 KB
    int t = threadIdx.x;
    int db = blockIdx.x, sp = blockIdx.y;
    f4v z = {0.f, 0.f, 0.f, 0.f};
    for (int i = t; i < DBN * 8 / 4; i += 512) ((f4v*)acc)[i] = z;
    int cpS = (nchunks + S - 1) / S;
    int c0 = sp * cpS;
    int c1 = c0 + cpS; if (c1 > nchunks) c1 = nchunks;
    int f = t & 7;
    int node2 = t >> 1, half = t & 1;
    // prologue stage
    if (c0 < c1) {
        int rows = n - (c0 << 8); if (rows > 256) rows = 256;
        if (node2 < rows)
            ((f4v*)win[0])[node2 * 2 + half] =
                __builtin_nontemporal_load(&((const f4v*)plane)[((size_t)(c0 << 8) + node2) * 2 + half]);
    }
    __syncthreads();
    int buf = 0;
    for (int c = c0; c < c1; ++c) {
        if (c + 1 < c1) {  // stage next into other buffer
            int rows = n - ((c + 1) << 8); if (rows > 256) rows = 256;
            if (node2 < rows)
                ((f4v*)win[buf ^ 1])[node2 * 2 + half] =
                    __builtin_nontemporal_load(&((const f4v*)plane)[((size_t)((c + 1) << 8) + node2) * 2 + half]);
        }
        unsigned jb = offA[db * NCH + c];
        unsigned je = jb + cntA[db * NCH + c];
        for (unsigned j = jb + (t >> 3); j < je; j += 64) {
            unsigned e = __builtin_nontemporal_load(&out2[j]);
            float v = win[buf][((e >> DBSH) & 255u) * 8 + f];
            atomicAdd(&acc[(e & (DBN - 1)) * 8 + f], v);
        }
        __syncthreads();
        buf ^= 1;
    }
    // writeout partial
    int dbase = db << DBSH;
    int rows = n - dbase; if (rows > DBN) rows = DBN;
    f4v* po = (f4v*)(part + (size_t)sp * n * 8 + (size_t)dbase * 8);
    for (int i = t; i < rows * 2; i += 512)
        __builtin_nontemporal_store(((f4v*)acc)[i], &po[i]);
}

// ---------- post conv1: sum partials + self, bias+ReLU, GEMM2 ----------------
__global__ void __launch_bounds__(256) k_post1(const float* __restrict__ part1,
                                               const float* __restrict__ t1p,
                                               const unsigned* __restrict__ degc,
                                               const float* __restrict__ b1,
                                               const float* __restrict__ W2,
                                               float* __restrict__ t2p, int n) {
    __shared__ float w2s[HID * NCLS];
    __shared__ float b1s[HID];
    if (threadIdx.x < HID * NCLS) w2s[threadIdx.x] = W2[threadIdx.x];
    if (threadIdx.x < HID) b1s[threadIdx.x] = b1[threadIdx.x];
    __syncthreads();
    int i = blockIdx.x * blockDim.x + threadIdx.x;
    if (i >= n) return;
    f4v sum[4];  // [plane0 lo, plane0 hi, plane1 lo, plane1 hi]
#pragma unroll
    for (int pl = 0; pl < 2; ++pl) {
        const f4v* self = (const f4v*)(t1p + (size_t)pl * n * 8);
        sum[pl * 2 + 0] = self[(size_t)i * 2 + 0];
        sum[pl * 2 + 1] = self[(size_t)i * 2 + 1];
#pragma unroll
        for (int s = 0; s < S1; ++s) {
            const f4v* p = (const f4v*)(part1 + (size_t)(pl * S1 + s) * n * 8);
            sum[pl * 2 + 0] += __builtin_nontemporal_load(&p[(size_t)i * 2 + 0]);
            sum[pl * 2 + 1] += __builtin_nontemporal_load(&p[(size_t)i * 2 + 1]);
        }
    }
    float di = rsqrtf((float)(degc[i] + 1u));
    float h[HID];
#pragma unroll
    for (int q = 0; q < 4; ++q)
#pragma unroll
        for (int r = 0; r < 4; ++r)
            h[q * 4 + r] = fmaxf(di * sum[q][r] + b1s[q * 4 + r], 0.f);
    float o[NCLS];
#pragma unroll
    for (int c = 0; c < NCLS; ++c) o[c] = 0.f;
#pragma unroll
    for (int k = 0; k < HID; ++k)
#pragma unroll
        for (int c = 0; c < NCLS; ++c) o[c] += h[k] * w2s[k * NCLS + c];
    f4v* o4 = (f4v*)(t2p + (size_t)i * 8);
    f4v r0 = {o[0] * di, o[1] * di, o[2] * di, o[3] * di};
    f4v r1 = {o[4] * di, o[5] * di, o[6] * di, o[7] * di};
    o4[0] = r0;
    o4[1] = r1;
}

// ---------- post conv2: sum partials + self, bias, fused mean-pool -----------
__global__ void __launch_bounds__(256) k_post2pool(const float* __restrict__ part2,
                                                   const float* __restrict__ t2p,
                                                   const unsigned* __restrict__ degc,
                                                   const float* __restrict__ b2,
                                                   const int* __restrict__ batch,
                                                   float* __restrict__ out,
                                                   float* __restrict__ cg, int n) {
    __shared__ float wacc[WINP * NCLS];
    __shared__ float wcnt[WINP];
    __shared__ int gbase_s;
    int t = threadIdx.x;
    int dbase = blockIdx.x << 10;  // 1024 nodes per block
    if (t < WINP * NCLS) wacc[t] = 0.f;
    if (t < WINP) wcnt[t] = 0.f;
    if (t == 0) gbase_s = batch[dbase < n ? dbase : (n - 1)];
    __syncthreads();
    int gb = gbase_s;
    int k = t & 7;
    int nrows = n - dbase; if (nrows > 1024) nrows = 1024;
    for (int dl = t >> 3; dl < nrows; dl += 32) {
        int d = dbase + dl;
        float v = t2p[(size_t)d * 8 + k];  // self
#pragma unroll
        for (int s = 0; s < S2; ++s)
            v += __builtin_nontemporal_load(&part2[(size_t)s * n * 8 + (size_t)d * 8 + k]);
        v = rsqrtf((float)(degc[d] + 1u)) * v + b2[k];
        int g = batch[d];
        int gi = g - gb;
        if (gi < WINP) {
            atomicAdd(&wacc[gi * NCLS + k], v);
            if (k == 0) atomicAdd(&wcnt[gi], 1.f);
        } else {
            atomicAdd(&out[(size_t)g * NCLS + k], v);
            if (k == 0) atomicAdd(&cg[g], 1.f);
        }
    }
    __syncthreads();
    if (t < WINP * NCLS) {
        int gg = t >> 3;
        if (wcnt[gg] > 0.f) atomicAdd(&out[(size_t)(gb + gg) * NCLS + (t & 7)], wacc[t]);
    }
    if (t < WINP && wcnt[t] > 0.f) atomicAdd(&cg[gb + t], wcnt[t]);
}

__global__ void k_div(float* __restrict__ out, const float* __restrict__ cg, int total) {
    int i = blockIdx.x * blockDim.x + threadIdx.x;
    if (i < total) out[i] /= fmaxf(cg[i / NCLS], 1.0f);
}

extern "C" void kernel_launch(void* const* d_in, const int* in_sizes, int n_in,
                              void* d_out, int out_size, void* d_ws, size_t ws_size,
                              hipStream_t stream) {
    const float* x = (const float*)d_in[0];
    const int* ei = (const int*)d_in[1];
    const int* batch = (const int*)d_in[2];
    const float* W1 = (const float*)d_in[4];
    const float* b1 = (const float*)d_in[5];
    const float* W2 = (const float*)d_in[6];
    const float* b2 = (const float*)d_in[7];

    int n = in_sizes[0] / F_IN;
    int e = in_sizes[1] / 2;
    int g = out_size / NCLS;
    const int* src = ei;
    const int* dst = ei + e;
    int ndb = (n + DBN - 1) >> DBSH;          // 25
    int nssc = (n + 8191) >> SSCSH;           // 13
    int nb2 = ndb * nssc;                     // 325
    int nchunks = (n + 255) >> 8;             // 391

    char* w = (char*)d_ws;
    unsigned* degc   = (unsigned*)w; w += (size_t)n * 4;
    unsigned* binCur = (unsigned*)w; w += (size_t)NB2MAX * 4;
    unsigned* offA   = (unsigned*)w; w += (size_t)32 * NCH * 4;
    unsigned* cntA   = (unsigned*)w; w += (size_t)32 * NCH * 4;
    float* t1p       = (float*)w;    w += (size_t)n * HID * 4;        // 2 planes
    float* t2p       = (float*)w;    w += (size_t)n * NCLS * 4;
    float* cg        = (float*)w;    w += (size_t)g * 4;
    unsigned* binbuf = (unsigned*)w; w += (size_t)nb2 * CAP2 * 4;     // 15.6 MB
    unsigned* out2   = (unsigned*)w; w += (size_t)nb2 * CAP2 * 4;     // 15.6 MB
    float* part1     = (float*)w;    w += (size_t)2 * S1 * n * 8 * 4; // 38.4 MB
    float* part2     = part1;        // aliases part1 (dead after k_post1); S2*n*8*4 = 38.4 MB

    hipMemsetAsync(degc, 0, (size_t)n * 4, stream);
    hipMemsetAsync(cg, 0, (size_t)g * 4, stream);
    hipMemsetAsync(d_out, 0, (size_t)out_size * 4, stream);

    const int B = 256;
    k_bininit<<<(nb2 + 511) / 512, 512, 0, stream>>>(binCur, nb2);
    k_binA<<<(e + TILE - 1) / TILE, 256, 0, stream>>>(src, dst, e, nssc, binCur, binbuf);
    k_binB<<<nb2, 256, 0, stream>>>(binbuf, binCur, nssc, n, out2, offA, cntA, degc);
    k_gemm1<<<(n + 15) / 16, 256, 0, stream>>>(x, W1, degc, t1p, n);
    dim3 ga(ndb, S1);
    k_agg<<<ga, 512, 0, stream>>>(out2, offA, cntA, t1p, part1, n, nchunks, S1);
    k_agg<<<ga, 512, 0, stream>>>(out2, offA, cntA, t1p + (size_t)n * 8,
                                  part1 + (size_t)S1 * n * 8, n, nchunks, S1);
    k_post1<<<(n + B - 1) / B, B, 0, stream>>>(part1, t1p, degc, b1, W2, t2p, n);
    dim3 gb2(ndb, S2);
    k_agg<<<gb2, 512, 0, stream>>>(out2, offA, cntA, t2p, part2, n, nchunks, S2);
    k_post2pool<<<(n + 1023) / 1024, 256, 0, stream>>>(part2, t2p, degc, b2, batch,
                                                       (float*)d_out, cg, n);
    k_div<<<(out_size + B - 1) / B, B, 0, stream>>>((float*)d_out, cg, out_size);
}

// Round 9
// 694.887 us; speedup vs baseline: 1.5377x; 1.5377x over previous
//
#include <hip/hip_runtime.h>

#define F_IN 256
#define HID 16
#define NCLS 8
#define BSHIFT 9
#define BMASK ((1u << BSHIFT) - 1u)
#define NPB (1 << BSHIFT)     // 512 nodes per bin
#define MAXBINS 256
#define BCAP 20480u           // per-bin edge capacity (mean ~16384)
#define TILE 4096
#define S1 6
#define S2 8
#define ST1 17                // padded LDS row stride (conv1)
#define ST2 9                 // padded LDS row stride (conv2)
#define WIN 16

typedef float f4v __attribute__((ext_vector_type(4)));
typedef _Float16 h8v __attribute__((ext_vector_type(8)));

// ---------- init per-bin cursors ---------------------------------------------
__global__ void k_bininit(unsigned* __restrict__ binCur) {
    if (threadIdx.x < MAXBINS) binCur[threadIdx.x] = threadIdx.x * BCAP;
}

// ---------- pass A: degree histogram + dst-binned edge buffer ----------------
__global__ void __launch_bounds__(256) k_binA(const int* __restrict__ src,
                                              const int* __restrict__ dst, int e,
                                              unsigned* __restrict__ degc,
                                              unsigned* __restrict__ binCur,
                                              unsigned* __restrict__ binbuf) {
    __shared__ unsigned scnt[MAXBINS], lbase[MAXBINS], gbase[MAXBINS];
    __shared__ unsigned sbuf[TILE];
    __shared__ unsigned char sbin[TILE];
    int t = threadIdx.x;
    if (t < MAXBINS) scnt[t] = 0u;
    __syncthreads();
    int base = blockIdx.x * TILE;
    unsigned ent[16], rank[16];
    int ebin[16];
#pragma unroll
    for (int i = 0; i < 16; ++i) {
        int j = base + t + i * 256;
        ebin[i] = -1;
        if (j < e) {
            int d = __builtin_nontemporal_load(&dst[j]);
            int s = __builtin_nontemporal_load(&src[j]);
            atomicAdd(&degc[d], 1u);
            ent[i] = ((unsigned)s << BSHIFT) | ((unsigned)d & (NPB - 1));
            ebin[i] = d >> BSHIFT;
            rank[i] = atomicAdd(&scnt[ebin[i]], 1u);
        }
    }
    __syncthreads();
    if (t == 0) {
        unsigned run = 0;
        for (int b = 0; b < MAXBINS; ++b) { lbase[b] = run; run += scnt[b]; }
    }
    __syncthreads();
    if (t < MAXBINS && scnt[t] > 0u) gbase[t] = atomicAdd(&binCur[t], scnt[t]);
    __syncthreads();
#pragma unroll
    for (int i = 0; i < 16; ++i)
        if (ebin[i] >= 0) {
            unsigned p = lbase[ebin[i]] + rank[i];
            sbuf[p] = ent[i];
            sbin[p] = (unsigned char)ebin[i];
        }
    __syncthreads();
    int total = e - base; if (total > TILE) total = TILE;
    for (int idx = t; idx < total; idx += 256) {
        int b = sbin[idx];
        __builtin_nontemporal_store(sbuf[idx], &binbuf[gbase[b] + ((unsigned)idx - lbase[b])]);
    }
}

// ---------- GEMM1: t1h[n][16] (fp16) = (x @ W1) * rsqrt(deg+1) ---------------
__global__ void __launch_bounds__(256) k_gemm1(const float* __restrict__ x,
                                               const float* __restrict__ W1,
                                               const unsigned* __restrict__ degc,
                                               _Float16* __restrict__ t1h, int n) {
    __shared__ float ws[HID][260];
    for (int idx = threadIdx.x; idx < F_IN * HID; idx += 256) {
        int c = idx >> 4, k = idx & 15;
        ws[k][c] = W1[idx];
    }
    __syncthreads();
    int r = blockIdx.x * 16 + (threadIdx.x >> 4);
    int k = threadIdx.x & 15;
    if (r >= n) return;
    const f4v* xr = (const f4v*)(x + (size_t)r * F_IN);
    const f4v* wr = (const f4v*)&ws[k][0];
    float acc = 0.f;
#pragma unroll 8
    for (int c4 = 0; c4 < F_IN / 4; ++c4) {
        f4v v = __builtin_nontemporal_load(&xr[c4]);
        f4v w = wr[c4];
        acc += v[0] * w[0] + v[1] * w[1] + v[2] * w[2] + v[3] * w[3];
    }
    t1h[(size_t)r * HID + k] = (_Float16)(acc * rsqrtf((float)(degc[r] + 1u)));
}

// ---------- conv1 aggregation: 1 edge per lane, fp16 row gather --------------
__global__ void __launch_bounds__(512) k_agg1(const unsigned* __restrict__ binbuf,
                                              const unsigned* __restrict__ binCur,
                                              const h8v* __restrict__ t1h,  // 2 per row
                                              float* __restrict__ hpart, int n) {
    __shared__ float acc[NPB * ST1];  // 34.8 KB -> 4 blocks/CU
    int t = threadIdx.x;
    int b = blockIdx.x, s = blockIdx.y;
    for (int i = t; i < NPB * ST1; i += 512) acc[i] = 0.f;
    __syncthreads();
    unsigned base = (unsigned)b * BCAP;
    unsigned cnt = binCur[b] - base;
    unsigned chunk = (cnt + S1 - 1) / S1;
    unsigned j0 = (unsigned)s * chunk;
    unsigned j1 = j0 + chunk; if (j1 > cnt) j1 = cnt;
    unsigned j = j0 + t;
    for (; j + 512 < j1; j += 1024) {
        unsigned v0 = __builtin_nontemporal_load(&binbuf[base + j]);
        unsigned v1 = __builtin_nontemporal_load(&binbuf[base + j + 512]);
        h8v a0 = t1h[(size_t)(v0 >> BSHIFT) * 2];
        h8v a1 = t1h[(size_t)(v0 >> BSHIFT) * 2 + 1];
        h8v b0 = t1h[(size_t)(v1 >> BSHIFT) * 2];
        h8v b1 = t1h[(size_t)(v1 >> BSHIFT) * 2 + 1];
        int n0 = (int)(v0 & BMASK) * ST1;
        int n1 = (int)(v1 & BMASK) * ST1;
#pragma unroll
        for (int r = 0; r < 8; ++r) atomicAdd(&acc[n0 + r], (float)a0[r]);
#pragma unroll
        for (int r = 0; r < 8; ++r) atomicAdd(&acc[n0 + 8 + r], (float)a1[r]);
#pragma unroll
        for (int r = 0; r < 8; ++r) atomicAdd(&acc[n1 + r], (float)b0[r]);
#pragma unroll
        for (int r = 0; r < 8; ++r) atomicAdd(&acc[n1 + 8 + r], (float)b1[r]);
    }
    if (j < j1) {
        unsigned v = __builtin_nontemporal_load(&binbuf[base + j]);
        h8v a0 = t1h[(size_t)(v >> BSHIFT) * 2];
        h8v a1 = t1h[(size_t)(v >> BSHIFT) * 2 + 1];
        int n0 = (int)(v & BMASK) * ST1;
#pragma unroll
        for (int r = 0; r < 8; ++r) atomicAdd(&acc[n0 + r], (float)a0[r]);
#pragma unroll
        for (int r = 0; r < 8; ++r) atomicAdd(&acc[n0 + 8 + r], (float)a1[r]);
    }
    __syncthreads();
    int dbase = b << BSHIFT;
    int nrows = n - dbase; if (nrows > NPB) nrows = NPB;
    float* po = hpart + ((size_t)s * n + dbase) * HID;
    for (int idx = t; idx < nrows * HID; idx += 512) {
        int dl = idx >> 4, f = idx & 15;
        __builtin_nontemporal_store(acc[dl * ST1 + f], &po[idx]);
    }
}

// ---------- post conv1: sum partials + self, bias+ReLU, GEMM2 ----------------
__global__ void __launch_bounds__(256) k_post1(const float* __restrict__ hpart,
                                               const h8v* __restrict__ t1h,
                                               const unsigned* __restrict__ degc,
                                               const float* __restrict__ b1,
                                               const float* __restrict__ W2,
                                               _Float16* __restrict__ t2h, int n) {
    __shared__ float w2s[HID * NCLS];
    __shared__ float b1s[HID];
    if (threadIdx.x < HID * NCLS) w2s[threadIdx.x] = W2[threadIdx.x];
    if (threadIdx.x < HID) b1s[threadIdx.x] = b1[threadIdx.x];
    __syncthreads();
    int i = blockIdx.x * blockDim.x + threadIdx.x;
    if (i >= n) return;
    float sum[HID];
    h8v s0 = t1h[(size_t)i * 2], s1 = t1h[(size_t)i * 2 + 1];
#pragma unroll
    for (int r = 0; r < 8; ++r) { sum[r] = (float)s0[r]; sum[8 + r] = (float)s1[r]; }
#pragma unroll
    for (int s = 0; s < S1; ++s) {
        const f4v* p = (const f4v*)(hpart + ((size_t)s * n + i) * HID);
#pragma unroll
        for (int q = 0; q < 4; ++q) {
            f4v v = __builtin_nontemporal_load(&p[q]);
            sum[q * 4 + 0] += v[0]; sum[q * 4 + 1] += v[1];
            sum[q * 4 + 2] += v[2]; sum[q * 4 + 3] += v[3];
        }
    }
    float di = rsqrtf((float)(degc[i] + 1u));
    float h[HID];
#pragma unroll
    for (int k = 0; k < HID; ++k) h[k] = fmaxf(di * sum[k] + b1s[k], 0.f);
    float o[NCLS];
#pragma unroll
    for (int c = 0; c < NCLS; ++c) o[c] = 0.f;
#pragma unroll
    for (int k = 0; k < HID; ++k)
#pragma unroll
        for (int c = 0; c < NCLS; ++c) o[c] += h[k] * w2s[k * NCLS + c];
    h8v ov;
#pragma unroll
    for (int c = 0; c < NCLS; ++c) ov[c] = (_Float16)(o[c] * di);
    ((h8v*)t2h)[i] = ov;
}

// ---------- conv2 aggregation: 1 edge per lane, fp16 row gather --------------
__global__ void __launch_bounds__(256) k_agg2(const unsigned* __restrict__ binbuf,
                                              const unsigned* __restrict__ binCur,
                                              const h8v* __restrict__ t2h,
                                              float* __restrict__ t2part, int n) {
    __shared__ float acc[NPB * ST2];  // 18 KB -> 8 blocks/CU
    int t = threadIdx.x;
    int b = blockIdx.x, s = blockIdx.y;
    for (int i = t; i < NPB * ST2; i += 256) acc[i] = 0.f;
    __syncthreads();
    unsigned base = (unsigned)b * BCAP;
    unsigned cnt = binCur[b] - base;
    unsigned chunk = (cnt + S2 - 1) / S2;
    unsigned j0 = (unsigned)s * chunk;
    unsigned j1 = j0 + chunk; if (j1 > cnt) j1 = cnt;
    unsigned j = j0 + t;
    for (; j + 256 < j1; j += 512) {
        unsigned v0 = __builtin_nontemporal_load(&binbuf[base + j]);
        unsigned v1 = __builtin_nontemporal_load(&binbuf[base + j + 256]);
        h8v a0 = t2h[v0 >> BSHIFT];
        h8v a1 = t2h[v1 >> BSHIFT];
        int n0 = (int)(v0 & BMASK) * ST2;
        int n1 = (int)(v1 & BMASK) * ST2;
#pragma unroll
        for (int r = 0; r < 8; ++r) atomicAdd(&acc[n0 + r], (float)a0[r]);
#pragma unroll
        for (int r = 0; r < 8; ++r) atomicAdd(&acc[n1 + r], (float)a1[r]);
    }
    if (j < j1) {
        unsigned v = __builtin_nontemporal_load(&binbuf[base + j]);
        h8v a0 = t2h[v >> BSHIFT];
        int n0 = (int)(v & BMASK) * ST2;
#pragma unroll
        for (int r = 0; r < 8; ++r) atomicAdd(&acc[n0 + r], (float)a0[r]);
    }
    __syncthreads();
    int dbase = b << BSHIFT;
    int nrows = n - dbase; if (nrows > NPB) nrows = NPB;
    float* po = t2part + ((size_t)s * n + dbase) * NCLS;
    for (int idx = t; idx < nrows * NCLS; idx += 256) {
        int dl = idx >> 3, f = idx & 7;
        __builtin_nontemporal_store(acc[dl * ST2 + f], &po[idx]);
    }
}

// ---------- post conv2: sum partials + self, bias, fused mean-pool -----------
__global__ void __launch_bounds__(512) k_post2pool(const float* __restrict__ t2part,
                                                   const _Float16* __restrict__ t2h,
                                                   const unsigned* __restrict__ degc,
                                                   const float* __restrict__ b2,
                                                   const int* __restrict__ batch,
                                                   float* __restrict__ out,
                                                   float* __restrict__ cg, int n) {
    __shared__ float wacc[WIN * NCLS];
    __shared__ float wcnt[WIN];
    __shared__ int gbase_s;
    int t = threadIdx.x;
    int dbase = blockIdx.x << BSHIFT;
    if (t < WIN * NCLS) wacc[t] = 0.f;
    if (t < WIN) wcnt[t] = 0.f;
    if (t == 0) gbase_s = batch[dbase < n ? dbase : (n - 1)];
    __syncthreads();
    int gb = gbase_s;
    int k = t & 7;
    int nrows = n - dbase; if (nrows > NPB) nrows = NPB;
    for (int dl = t >> 3; dl < nrows; dl += 64) {
        int d = dbase + dl;
        float v = (float)t2h[(size_t)d * NCLS + k];  // self
#pragma unroll
        for (int s = 0; s < S2; ++s)
            v += __builtin_nontemporal_load(&t2part[((size_t)s * n + d) * NCLS + k]);
        v = rsqrtf((float)(degc[d] + 1u)) * v + b2[k];
        int g = batch[d];
        int gi = g - gb;
        if (gi < WIN) {
            atomicAdd(&wacc[gi * NCLS + k], v);
            if (k == 0) atomicAdd(&wcnt[gi], 1.f);
        } else {
            atomicAdd(&out[(size_t)g * NCLS + k], v);
            if (k == 0) atomicAdd(&cg[g], 1.f);
        }
    }
    __syncthreads();
    if (t < WIN * NCLS) {
        int gg = t >> 3;
        if (wcnt[gg] > 0.f) atomicAdd(&out[(size_t)(gb + gg) * NCLS + (t & 7)], wacc[t]);
    }
    if (t < WIN && wcnt[t] > 0.f) atomicAdd(&cg[gb + t], wcnt[t]);
}

__global__ void k_div(float* __restrict__ out, const float* __restrict__ cg, int total) {
    int i = blockIdx.x * blockDim.x + threadIdx.x;
    if (i < total) out[i] /= fmaxf(cg[i / NCLS], 1.0f);
}

extern "C" void kernel_launch(void* const* d_in, const int* in_sizes, int n_in,
                              void* d_out, int out_size, void* d_ws, size_t ws_size,
                              hipStream_t stream) {
    const float* x = (const float*)d_in[0];
    const int* ei = (const int*)d_in[1];
    const int* batch = (const int*)d_in[2];
    const float* W1 = (const float*)d_in[4];
    const float* b1 = (const float*)d_in[5];
    const float* W2 = (const float*)d_in[6];
    const float* b2 = (const float*)d_in[7];

    int n = in_sizes[0] / F_IN;
    int e = in_sizes[1] / 2;
    int g = out_size / NCLS;
    const int* src = ei;
    const int* dst = ei + e;
    int nbins = (n + NPB - 1) >> BSHIFT;  // 196 for n=100000

    char* w = (char*)d_ws;
    unsigned* degc   = (unsigned*)w; w += (size_t)n * 4;
    unsigned* binCur = (unsigned*)w; w += (size_t)MAXBINS * 4;
    _Float16* t1h    = (_Float16*)w; w += (size_t)n * HID * 2;          // 3.2 MB
    _Float16* t2h    = (_Float16*)w; w += (size_t)n * NCLS * 2;         // 1.6 MB
    float* cg        = (float*)w;    w += (size_t)g * 4;
    w = (char*)(((size_t)w + 255) & ~(size_t)255);
    float* hpart     = (float*)w;    w += (size_t)S1 * n * HID * 4;     // 38.4 MB
    float* t2part    = (float*)w;    w += (size_t)S2 * n * NCLS * 4;    // 25.6 MB
    unsigned* binbuf = (unsigned*)w; w += (size_t)nbins * BCAP * 4;     // 16.1 MB

    hipMemsetAsync(degc, 0, (size_t)n * 4, stream);
    hipMemsetAsync(cg, 0, (size_t)g * 4, stream);
    hipMemsetAsync(d_out, 0, (size_t)out_size * 4, stream);

    const int B = 256;
    k_bininit<<<1, MAXBINS, 0, stream>>>(binCur);
    k_binA<<<(e + TILE - 1) / TILE, 256, 0, stream>>>(src, dst, e, degc, binCur, binbuf);
    k_gemm1<<<(n + 15) / 16, 256, 0, stream>>>(x, W1, degc, t1h, n);
    dim3 g1(nbins, S1);
    k_agg1<<<g1, 512, 0, stream>>>(binbuf, binCur, (const h8v*)t1h, hpart, n);
    k_post1<<<(n + B - 1) / B, B, 0, stream>>>(hpart, (const h8v*)t1h, degc, b1, W2, t2h, n);
    dim3 g2(nbins, S2);
    k_agg2<<<g2, 256, 0, stream>>>(binbuf, binCur, (const h8v*)t2h, t2part, n);
    k_post2pool<<<nbins, 512, 0, stream>>>(t2part, t2h, degc, b2, batch,
                                           (float*)d_out, cg, n);
    k_div<<<(out_size + B - 1) / B, B, 0, stream>>>((float*)d_out, cg, out_size);
}

// Round 11
// 241.021 us; speedup vs baseline: 4.4334x; 2.8831x over previous
//
#include <hip/hip_runtime.h>

#define F_IN 256
#define HID 16
#define NCLS 8
#define BSH 9
#define NPB 512               // nodes per bin
#define MAXBINS 256
#define BCAP 18432u           // per-bin edge capacity (mean 16384, +16 sigma)
#define TILE 4096
#define WIN 8

typedef float f4v __attribute__((ext_vector_type(4)));
typedef _Float16 h2v __attribute__((ext_vector_type(2)));

// ---------- init per-bin cursors ---------------------------------------------
__global__ void k_bininit(unsigned* __restrict__ binCur, int nbins) {
    int t = threadIdx.x;
    if (t < nbins) binCur[t] = (unsigned)t * BCAP;
}

// ---------- pass A: bin edges by dst>>9 (contiguous runs, no write amp) ------
__global__ void __launch_bounds__(256) k_binA(const int* __restrict__ src,
                                              const int* __restrict__ dst, int e,
                                              unsigned* __restrict__ binCur,
                                              unsigned* __restrict__ binbuf) {
    __shared__ unsigned scnt[MAXBINS], lbase[MAXBINS], gbase[MAXBINS];
    __shared__ unsigned sbuf[TILE];
    __shared__ unsigned char sbin[TILE];
    int t = threadIdx.x;
    if (t < MAXBINS) scnt[t] = 0u;
    __syncthreads();
    int base = blockIdx.x * TILE;
    unsigned ent[16], rank[16];
    int ebin[16];
#pragma unroll
    for (int i = 0; i < 16; ++i) {
        int j = base + t + i * 256;
        ebin[i] = -1;
        if (j < e) {
            int d = __builtin_nontemporal_load(&dst[j]);
            int s = __builtin_nontemporal_load(&src[j]);
            ent[i] = ((unsigned)s << BSH) | ((unsigned)d & (NPB - 1));
            ebin[i] = d >> BSH;
            rank[i] = atomicAdd(&scnt[ebin[i]], 1u);
        }
    }
    __syncthreads();
    if (t == 0) {
        unsigned run = 0;
        for (int b = 0; b < MAXBINS; ++b) { lbase[b] = run; run += scnt[b]; }
    }
    __syncthreads();
    if (t < MAXBINS && scnt[t] > 0u) gbase[t] = atomicAdd(&binCur[t], scnt[t]);
    __syncthreads();
#pragma unroll
    for (int i = 0; i < 16; ++i)
        if (ebin[i] >= 0) {
            unsigned p = lbase[ebin[i]] + rank[i];
            sbuf[p] = ent[i];
            sbin[p] = (unsigned char)ebin[i];
        }
    __syncthreads();
    int total = e - base; if (total > TILE) total = TILE;
    for (int idx = t; idx < total; idx += 256) {
        int b = sbin[idx];
        __builtin_nontemporal_store(sbuf[idx], &binbuf[gbase[b] + ((unsigned)idx - lbase[b])]);
    }
}

// ---------- pass B: per-bin counting sort by exact dst -> CSR ----------------
// One block owns one bin: scatter confined to its own ~72KB region (L2-local),
// degrees and offsets become plain stores (no global atomics, no scan kernels).
__global__ void __launch_bounds__(256) k_binB(const unsigned* __restrict__ binbuf,
                                              const unsigned* __restrict__ binCur,
                                              int n,
                                              unsigned* __restrict__ srcs,
                                              unsigned* __restrict__ off,
                                              unsigned* __restrict__ degc) {
    __shared__ unsigned hist[NPB];
    __shared__ unsigned pref[NPB];
    __shared__ unsigned s1[256];
    int t = threadIdx.x;
    int b = blockIdx.x;
    unsigned base = (unsigned)b * BCAP;
    unsigned end = binCur[b];
    for (int i = t; i < NPB; i += 256) hist[i] = 0u;
    __syncthreads();
    for (unsigned j = base + t; j < end; j += 256)
        atomicAdd(&hist[__builtin_nontemporal_load(&binbuf[j]) & (NPB - 1)], 1u);
    __syncthreads();
    unsigned h0 = hist[2 * t], h1 = hist[2 * t + 1];
    unsigned pair = h0 + h1;
    s1[t] = pair;
    __syncthreads();
    for (int o = 1; o < 256; o <<= 1) {
        unsigned v = (t >= o) ? s1[t - o] : 0u;
        __syncthreads();
        s1[t] += v;
        __syncthreads();
    }
    unsigned exc = s1[t] - pair;
    pref[2 * t] = exc;
    pref[2 * t + 1] = exc + h0;
    __syncthreads();
    int dbase = b << BSH;
    for (int i = t; i < NPB; i += 256) {
        int d = dbase + i;
        if (d < n) { off[d] = base + pref[i]; degc[d] = hist[i]; }
    }
    __syncthreads();
    for (int i = t; i < NPB; i += 256) hist[i] = 0u;  // reuse as cursors
    __syncthreads();
    for (unsigned j = base + t; j < end; j += 256) {
        unsigned v = __builtin_nontemporal_load(&binbuf[j]);
        unsigned dl = v & (NPB - 1);
        unsigned r = atomicAdd(&hist[dl], 1u);
        srcs[base + pref[dl] + r] = v >> BSH;
    }
}

// ---------- GEMM1: t1h[n][16] fp16 = (x @ W1) * rsqrt(deg+1) -----------------
__global__ void __launch_bounds__(256) k_gemm1(const float* __restrict__ x,
                                               const float* __restrict__ W1,
                                               const unsigned* __restrict__ degc,
                                               _Float16* __restrict__ t1h, int n) {
    __shared__ float ws[HID][260];
    for (int idx = threadIdx.x; idx < F_IN * HID; idx += 256) {
        int c = idx >> 4, k = idx & 15;
        ws[k][c] = W1[idx];
    }
    __syncthreads();
    int r = blockIdx.x * 16 + (threadIdx.x >> 4);
    int k = threadIdx.x & 15;
    if (r >= n) return;
    const f4v* xr = (const f4v*)(x + (size_t)r * F_IN);
    const f4v* wr = (const f4v*)&ws[k][0];
    float acc = 0.f;
#pragma unroll 8
    for (int c4 = 0; c4 < F_IN / 4; ++c4) {
        f4v v = __builtin_nontemporal_load(&xr[c4]);
        f4v w = wr[c4];
        acc += v[0] * w[0] + v[1] * w[1] + v[2] * w[2] + v[3] * w[3];
    }
    t1h[(size_t)r * HID + k] = (_Float16)(acc * rsqrtf((float)(degc[r] + 1u)));
}

// ---------- conv1: CSR gather, 16 lanes/dst (8 feat-pairs x 2 edges) ---------
__global__ void __launch_bounds__(256) k_agg1(const unsigned* __restrict__ srcs,
                                              const unsigned* __restrict__ off,
                                              const unsigned* __restrict__ degc,
                                              const unsigned* __restrict__ t1h,  // u32 pairs [n*8]
                                              const float* __restrict__ b1,
                                              unsigned* __restrict__ hbuf, int n) {
    int t = threadIdx.x;
    int d = blockIdx.x * 16 + (t >> 4);
    if (d >= n) return;
    int lane8 = t & 7;
    int oct = (t >> 3) & 1;
    unsigned p = off[d];
    unsigned c = degc[d];
    float a0 = 0.f, a1 = 0.f;
    union { unsigned u; h2v h; } cv;
    unsigned i = oct;
    for (; i + 2 < c; i += 4) {
        unsigned sA = srcs[p + i];
        unsigned sB = srcs[p + i + 2];
        unsigned wA = t1h[(size_t)sA * 8 + lane8];
        unsigned wB = t1h[(size_t)sB * 8 + lane8];
        cv.u = wA; a0 += (float)cv.h[0]; a1 += (float)cv.h[1];
        cv.u = wB; a0 += (float)cv.h[0]; a1 += (float)cv.h[1];
    }
    if (i < c) {
        unsigned w = t1h[(size_t)srcs[p + i] * 8 + lane8];
        cv.u = w; a0 += (float)cv.h[0]; a1 += (float)cv.h[1];
    }
    a0 += __shfl_xor(a0, 8, 64);
    a1 += __shfl_xor(a1, 8, 64);
    if (oct == 0) {
        cv.u = t1h[(size_t)d * 8 + lane8];  // self loop
        a0 += (float)cv.h[0]; a1 += (float)cv.h[1];
        float di = rsqrtf((float)(c + 1u));
        float h0 = fmaxf(di * a0 + b1[2 * lane8], 0.f);
        float h1 = fmaxf(di * a1 + b1[2 * lane8 + 1], 0.f);
        union { unsigned u; h2v h; } pk;
        pk.h[0] = (_Float16)h0; pk.h[1] = (_Float16)h1;
        hbuf[(size_t)d * 8 + lane8] = pk.u;
    }
}

// ---------- GEMM2: t2h[n][8] fp16 = (h @ W2) * rsqrt(deg+1) ------------------
__global__ void __launch_bounds__(256) k_gemm2(const unsigned* __restrict__ hbuf,
                                               const float* __restrict__ W2,
                                               const unsigned* __restrict__ degc,
                                               unsigned* __restrict__ t2h, int n) {
    __shared__ float w2s[HID * NCLS];
    if (threadIdx.x < HID * NCLS) w2s[threadIdx.x] = W2[threadIdx.x];
    __syncthreads();
    int i = blockIdx.x * 256 + threadIdx.x;
    if (i >= n) return;
    union { uint4 q; unsigned u[4]; } A, B;
    const uint4* hb = (const uint4*)(hbuf + (size_t)i * 8);
    A.q = hb[0]; B.q = hb[1];
    float h[HID];
    union { unsigned u; h2v h; } cv;
#pragma unroll
    for (int q = 0; q < 4; ++q) {
        cv.u = A.u[q]; h[2 * q] = (float)cv.h[0]; h[2 * q + 1] = (float)cv.h[1];
        cv.u = B.u[q]; h[8 + 2 * q] = (float)cv.h[0]; h[8 + 2 * q + 1] = (float)cv.h[1];
    }
    float o[NCLS];
#pragma unroll
    for (int c = 0; c < NCLS; ++c) o[c] = 0.f;
#pragma unroll
    for (int k = 0; k < HID; ++k)
#pragma unroll
        for (int c = 0; c < NCLS; ++c) o[c] += h[k] * w2s[k * NCLS + c];
    float di = rsqrtf((float)(degc[i] + 1u));
    union { uint4 q; unsigned u[4]; } O;
#pragma unroll
    for (int q = 0; q < 4; ++q) {
        union { unsigned u; h2v h; } pk;
        pk.h[0] = (_Float16)(o[2 * q] * di);
        pk.h[1] = (_Float16)(o[2 * q + 1] * di);
        O.u[q] = pk.u;
    }
    ((uint4*)(t2h + (size_t)i * 4))[0] = O.q;
}

// ---------- conv2: CSR gather 8 lanes/dst + fused windowed mean-pool ---------
__global__ void __launch_bounds__(256) k_agg2pool(const unsigned* __restrict__ srcs,
                                                  const unsigned* __restrict__ off,
                                                  const unsigned* __restrict__ degc,
                                                  const unsigned* __restrict__ t2h,  // u32 pairs [n*4]
                                                  const float* __restrict__ b2,
                                                  const int* __restrict__ batch,
                                                  float* __restrict__ out,
                                                  float* __restrict__ cg, int n) {
    __shared__ float wacc[WIN * NCLS];
    __shared__ float wcnt[WIN];
    __shared__ int gb_s;
    int t = threadIdx.x;
    int bbase = blockIdx.x * 32;
    if (t < WIN * NCLS) wacc[t] = 0.f;
    if (t < WIN) wcnt[t] = 0.f;
    if (t == 0) gb_s = batch[bbase < n ? bbase : (n - 1)];
    __syncthreads();
    int d = bbase + (t >> 3);
    int lane4 = t & 3;
    int pr = (t >> 2) & 1;
    if (d < n) {
        unsigned p = off[d];
        unsigned c = degc[d];
        float a0 = 0.f, a1 = 0.f;
        union { unsigned u; h2v h; } cv;
        unsigned i = pr;
        for (; i + 2 < c; i += 4) {
            unsigned wA = t2h[(size_t)srcs[p + i] * 4 + lane4];
            unsigned wB = t2h[(size_t)srcs[p + i + 2] * 4 + lane4];
            cv.u = wA; a0 += (float)cv.h[0]; a1 += (float)cv.h[1];
            cv.u = wB; a0 += (float)cv.h[0]; a1 += (float)cv.h[1];
        }
        if (i < c) {
            unsigned w = t2h[(size_t)srcs[p + i] * 4 + lane4];
            cv.u = w; a0 += (float)cv.h[0]; a1 += (float)cv.h[1];
        }
        a0 += __shfl_xor(a0, 4, 64);
        a1 += __shfl_xor(a1, 4, 64);
        if (pr == 0) {
            cv.u = t2h[(size_t)d * 4 + lane4];  // self loop
            a0 += (float)cv.h[0]; a1 += (float)cv.h[1];
            float di = rsqrtf((float)(c + 1u));
            float v0 = di * a0 + b2[2 * lane4];
            float v1 = di * a1 + b2[2 * lane4 + 1];
            int g = batch[d];
            int gi = g - gb_s;
            if (gi < WIN) {
                atomicAdd(&wacc[gi * NCLS + 2 * lane4], v0);
                atomicAdd(&wacc[gi * NCLS + 2 * lane4 + 1], v1);
                if ((t & 7) == 0) atomicAdd(&wcnt[gi], 1.f);
            } else {
                atomicAdd(&out[(size_t)g * NCLS + 2 * lane4], v0);
                atomicAdd(&out[(size_t)g * NCLS + 2 * lane4 + 1], v1);
                if ((t & 7) == 0) atomicAdd(&cg[g], 1.f);
            }
        }
    }
    __syncthreads();
    if (t < WIN * NCLS && wcnt[t >> 3] > 0.f)
        atomicAdd(&out[(size_t)(gb_s + (t >> 3)) * NCLS + (t & 7)], wacc[t]);
    if (t < WIN && wcnt[t] > 0.f) atomicAdd(&cg[gb_s + t], wcnt[t]);
}

__global__ void k_div(float* __restrict__ out, const float* __restrict__ cg, int total) {
    int i = blockIdx.x * blockDim.x + threadIdx.x;
    if (i < total) out[i] /= fmaxf(cg[i / NCLS], 1.0f);
}

extern "C" void kernel_launch(void* const* d_in, const int* in_sizes, int n_in,
                              void* d_out, int out_size, void* d_ws, size_t ws_size,
                              hipStream_t stream) {
    const float* x = (const float*)d_in[0];
    const int* ei = (const int*)d_in[1];
    const int* batch = (const int*)d_in[2];
    const float* W1 = (const float*)d_in[4];
    const float* b1 = (const float*)d_in[5];
    const float* W2 = (const float*)d_in[6];
    const float* b2 = (const float*)d_in[7];

    int n = in_sizes[0] / F_IN;
    int e = in_sizes[1] / 2;
    int g = out_size / NCLS;
    const int* src = ei;
    const int* dst = ei + e;
    int nbins = (n + NPB - 1) >> BSH;  // 196 for n=100000

    char* w = (char*)d_ws;
    unsigned* binCur = (unsigned*)w; w += (size_t)MAXBINS * 4;
    unsigned* degc   = (unsigned*)w; w += (size_t)n * 4;
    unsigned* off    = (unsigned*)w; w += (size_t)n * 4;
    unsigned* t1h    = (unsigned*)w; w += (size_t)n * 8 * 4;   // fp16 pairs, 3.2 MB
    unsigned* hbuf   = (unsigned*)w; w += (size_t)n * 8 * 4;   // fp16 pairs, 3.2 MB
    unsigned* t2h    = (unsigned*)w; w += (size_t)n * 4 * 4;   // fp16 pairs, 1.6 MB
    float* cg        = (float*)w;    w += (size_t)g * 4;
    w = (char*)(((size_t)w + 255) & ~(size_t)255);
    unsigned* binbuf = (unsigned*)w; w += (size_t)nbins * BCAP * 4;  // 14.5 MB
    unsigned* srcs   = (unsigned*)w; w += (size_t)nbins * BCAP * 4;  // 14.5 MB

    hipMemsetAsync(cg, 0, (size_t)g * 4, stream);
    hipMemsetAsync(d_out, 0, (size_t)out_size * 4, stream);

    k_bininit<<<1, 256, 0, stream>>>(binCur, nbins);
    k_binA<<<(e + TILE - 1) / TILE, 256, 0, stream>>>(src, dst, e, binCur, binbuf);
    k_binB<<<nbins, 256, 0, stream>>>(binbuf, binCur, n, srcs, off, degc);
    k_gemm1<<<(n + 15) / 16, 256, 0, stream>>>(x, W1, degc, (_Float16*)t1h, n);
    k_agg1<<<(n + 15) / 16, 256, 0, stream>>>(srcs, off, degc, t1h, b1, hbuf, n);
    k_gemm2<<<(n + 255) / 256, 256, 0, stream>>>(hbuf, W2, degc, t2h, n);
    k_agg2pool<<<(n + 31) / 32, 256, 0, stream>>>(srcs, off, degc, t2h, b2, batch,
                                                  (float*)d_out, cg, n);
    k_div<<<(out_size + 255) / 256, 256, 0, stream>>>((float*)d_out, cg, out_size);
}

// Round 12
// 222.357 us; speedup vs baseline: 4.8055x; 1.0839x over previous
//
#include <hip/hip_runtime.h>

#define F_IN 256
#define HID 16
#define NCLS 8
#define BSH 9
#define NPB 512               // nodes per bin
#define MAXBINS 256
#define BCAP 18432u           // per-bin edge capacity (mean 16384, +16 sigma)
#define TILE 4096
#define WIN 8

typedef float f4v __attribute__((ext_vector_type(4)));
typedef _Float16 h2v __attribute__((ext_vector_type(2)));

// ---------- init per-bin cursors ---------------------------------------------
__global__ void k_bininit(unsigned* __restrict__ binCur, int nbins) {
    int t = threadIdx.x;
    if (t < nbins) binCur[t] = (unsigned)t * BCAP;
}

// ---------- pass A: bin edges by dst>>9 (contiguous runs, no write amp) ------
__global__ void __launch_bounds__(256) k_binA(const int* __restrict__ src,
                                              const int* __restrict__ dst, int e,
                                              unsigned* __restrict__ binCur,
                                              unsigned* __restrict__ binbuf) {
    __shared__ unsigned scnt[MAXBINS], lbase[MAXBINS], gbase[MAXBINS];
    __shared__ unsigned sbuf[TILE];
    __shared__ unsigned char sbin[TILE];
    int t = threadIdx.x;
    if (t < MAXBINS) scnt[t] = 0u;
    __syncthreads();
    int base = blockIdx.x * TILE;
    unsigned ent[16], rank[16];
    int ebin[16];
#pragma unroll
    for (int i = 0; i < 16; ++i) {
        int j = base + t + i * 256;
        ebin[i] = -1;
        if (j < e) {
            int d = __builtin_nontemporal_load(&dst[j]);
            int s = __builtin_nontemporal_load(&src[j]);
            ent[i] = ((unsigned)s << BSH) | ((unsigned)d & (NPB - 1));
            ebin[i] = d >> BSH;
            rank[i] = atomicAdd(&scnt[ebin[i]], 1u);
        }
    }
    __syncthreads();
    if (t == 0) {
        unsigned run = 0;
        for (int b = 0; b < MAXBINS; ++b) { lbase[b] = run; run += scnt[b]; }
    }
    __syncthreads();
    if (t < MAXBINS && scnt[t] > 0u) gbase[t] = atomicAdd(&binCur[t], scnt[t]);
    __syncthreads();
#pragma unroll
    for (int i = 0; i < 16; ++i)
        if (ebin[i] >= 0) {
            unsigned p = lbase[ebin[i]] + rank[i];
            sbuf[p] = ent[i];
            sbin[p] = (unsigned char)ebin[i];
        }
    __syncthreads();
    int total = e - base; if (total > TILE) total = TILE;
    for (int idx = t; idx < total; idx += 256) {
        int b = sbin[idx];
        __builtin_nontemporal_store(sbuf[idx], &binbuf[gbase[b] + ((unsigned)idx - lbase[b])]);
    }
}

// ---------- pass B: per-bin counting sort by exact dst -> CSR ----------------
__global__ void __launch_bounds__(256) k_binB(const unsigned* __restrict__ binbuf,
                                              const unsigned* __restrict__ binCur,
                                              int n,
                                              unsigned* __restrict__ srcs,
                                              unsigned* __restrict__ off,
                                              unsigned* __restrict__ degc) {
    __shared__ unsigned hist[NPB];
    __shared__ unsigned pref[NPB];
    __shared__ unsigned s1[256];
    int t = threadIdx.x;
    int b = blockIdx.x;
    unsigned base = (unsigned)b * BCAP;
    unsigned end = binCur[b];
    for (int i = t; i < NPB; i += 256) hist[i] = 0u;
    __syncthreads();
    for (unsigned j = base + t; j < end; j += 256)
        atomicAdd(&hist[__builtin_nontemporal_load(&binbuf[j]) & (NPB - 1)], 1u);
    __syncthreads();
    unsigned h0 = hist[2 * t], h1 = hist[2 * t + 1];
    unsigned pair = h0 + h1;
    s1[t] = pair;
    __syncthreads();
    for (int o = 1; o < 256; o <<= 1) {
        unsigned v = (t >= o) ? s1[t - o] : 0u;
        __syncthreads();
        s1[t] += v;
        __syncthreads();
    }
    unsigned exc = s1[t] - pair;
    pref[2 * t] = exc;
    pref[2 * t + 1] = exc + h0;
    __syncthreads();
    int dbase = b << BSH;
    for (int i = t; i < NPB; i += 256) {
        int d = dbase + i;
        if (d < n) { off[d] = base + pref[i]; degc[d] = hist[i]; }
    }
    __syncthreads();
    for (int i = t; i < NPB; i += 256) hist[i] = 0u;  // reuse as cursors
    __syncthreads();
    for (unsigned j = base + t; j < end; j += 256) {
        unsigned v = __builtin_nontemporal_load(&binbuf[j]);
        unsigned dl = v & (NPB - 1);
        unsigned r = atomicAdd(&hist[dl], 1u);
        srcs[base + pref[dl] + r] = v >> BSH;
    }
}

// ---------- GEMM1: LDS-staged x tile; t1h[n][16] fp16 = (x@W1)*rsqrt(deg+1) --
__global__ void __launch_bounds__(256) k_gemm1(const float* __restrict__ x,
                                               const float* __restrict__ W1,
                                               const unsigned* __restrict__ degc,
                                               _Float16* __restrict__ t1h, int n) {
    __shared__ float ws[HID][260];
    __shared__ float xs[16][260];
    for (int idx = threadIdx.x; idx < F_IN * HID; idx += 256) {
        int c = idx >> 4, k = idx & 15;
        ws[k][c] = W1[idx];
    }
    int rbase = blockIdx.x * 16;
    int nrows = n - rbase; if (nrows > 16) nrows = 16;
    // stage 16 rows coalesced: consecutive threads -> consecutive float4
#pragma unroll
    for (int it = 0; it < 4; ++it) {
        int q = threadIdx.x + it * 256;   // float4 index within tile
        int row = q >> 6, c4 = q & 63;
        if (row < nrows) {
            f4v v = __builtin_nontemporal_load(
                &((const f4v*)(x + (size_t)(rbase + row) * F_IN))[c4]);
            *(f4v*)&xs[row][c4 * 4] = v;
        }
    }
    __syncthreads();
    int r = threadIdx.x >> 4;
    int k = threadIdx.x & 15;
    if (r >= nrows) return;
    const f4v* xr = (const f4v*)&xs[r][0];
    const f4v* wr = (const f4v*)&ws[k][0];
    float acc = 0.f;
#pragma unroll 8
    for (int c4 = 0; c4 < F_IN / 4; ++c4) {
        f4v v = xr[c4];
        f4v w = wr[c4];
        acc += v[0] * w[0] + v[1] * w[1] + v[2] * w[2] + v[3] * w[3];
    }
    int rr = rbase + r;
    t1h[(size_t)rr * HID + k] = (_Float16)(acc * rsqrtf((float)(degc[rr] + 1u)));
}

// ---------- conv1: CSR gather, 16 lanes/dst (8 feat-pairs x 2 edges) ---------
__global__ void __launch_bounds__(256) k_agg1(const unsigned* __restrict__ srcs,
                                              const unsigned* __restrict__ off,
                                              const unsigned* __restrict__ degc,
                                              const unsigned* __restrict__ t1h,  // u32 pairs [n*8]
                                              const float* __restrict__ b1,
                                              unsigned* __restrict__ hbuf, int n) {
    int t = threadIdx.x;
    int d = blockIdx.x * 16 + (t >> 4);
    if (d >= n) return;
    int lane8 = t & 7;
    int oct = (t >> 3) & 1;
    unsigned p = off[d];
    unsigned c = degc[d];
    float a0 = 0.f, a1 = 0.f;
    union { unsigned u; h2v h; } cv;
    unsigned i = oct;
    for (; i + 2 < c; i += 4) {
        unsigned sA = srcs[p + i];
        unsigned sB = srcs[p + i + 2];
        unsigned wA = t1h[(size_t)sA * 8 + lane8];
        unsigned wB = t1h[(size_t)sB * 8 + lane8];
        cv.u = wA; a0 += (float)cv.h[0]; a1 += (float)cv.h[1];
        cv.u = wB; a0 += (float)cv.h[0]; a1 += (float)cv.h[1];
    }
    if (i < c) {
        unsigned w = t1h[(size_t)srcs[p + i] * 8 + lane8];
        cv.u = w; a0 += (float)cv.h[0]; a1 += (float)cv.h[1];
    }
    a0 += __shfl_xor(a0, 8, 64);
    a1 += __shfl_xor(a1, 8, 64);
    if (oct == 0) {
        cv.u = t1h[(size_t)d * 8 + lane8];  // self loop
        a0 += (float)cv.h[0]; a1 += (float)cv.h[1];
        float di = rsqrtf((float)(c + 1u));
        float h0 = fmaxf(di * a0 + b1[2 * lane8], 0.f);
        float h1 = fmaxf(di * a1 + b1[2 * lane8 + 1], 0.f);
        union { unsigned u; h2v h; } pk;
        pk.h[0] = (_Float16)h0; pk.h[1] = (_Float16)h1;
        hbuf[(size_t)d * 8 + lane8] = pk.u;
    }
}

// ---------- GEMM2: t2h[n][8] fp16 = (h @ W2) * rsqrt(deg+1) ------------------
__global__ void __launch_bounds__(256) k_gemm2(const unsigned* __restrict__ hbuf,
                                               const float* __restrict__ W2,
                                               const unsigned* __restrict__ degc,
                                               unsigned* __restrict__ t2h, int n) {
    __shared__ float w2s[HID * NCLS];
    if (threadIdx.x < HID * NCLS) w2s[threadIdx.x] = W2[threadIdx.x];
    __syncthreads();
    int i = blockIdx.x * 256 + threadIdx.x;
    if (i >= n) return;
    union { uint4 q; unsigned u[4]; } A, B;
    const uint4* hb = (const uint4*)(hbuf + (size_t)i * 8);
    A.q = hb[0]; B.q = hb[1];
    float h[HID];
    union { unsigned u; h2v h; } cv;
#pragma unroll
    for (int q = 0; q < 4; ++q) {
        cv.u = A.u[q]; h[2 * q] = (float)cv.h[0]; h[2 * q + 1] = (float)cv.h[1];
        cv.u = B.u[q]; h[8 + 2 * q] = (float)cv.h[0]; h[8 + 2 * q + 1] = (float)cv.h[1];
    }
    float o[NCLS];
#pragma unroll
    for (int c = 0; c < NCLS; ++c) o[c] = 0.f;
#pragma unroll
    for (int k = 0; k < HID; ++k)
#pragma unroll
        for (int c = 0; c < NCLS; ++c) o[c] += h[k] * w2s[k * NCLS + c];
    float di = rsqrtf((float)(degc[i] + 1u));
    union { uint4 q; unsigned u[4]; } O;
#pragma unroll
    for (int q = 0; q < 4; ++q) {
        union { unsigned u; h2v h; } pk;
        pk.h[0] = (_Float16)(o[2 * q] * di);
        pk.h[1] = (_Float16)(o[2 * q + 1] * di);
        O.u[q] = pk.u;
    }
    ((uint4*)(t2h + (size_t)i * 4))[0] = O.q;
}

// ---------- conv2: CSR gather 8 lanes/dst + fused windowed mean-pool ---------
__global__ void __launch_bounds__(256) k_agg2pool(const unsigned* __restrict__ srcs,
                                                  const unsigned* __restrict__ off,
                                                  const unsigned* __restrict__ degc,
                                                  const unsigned* __restrict__ t2h,  // u32 pairs [n*4]
                                                  const float* __restrict__ b2,
                                                  const int* __restrict__ batch,
                                                  float* __restrict__ out,
                                                  float* __restrict__ cg, int n) {
    __shared__ float wacc[WIN * NCLS];
    __shared__ float wcnt[WIN];
    __shared__ int gb_s;
    int t = threadIdx.x;
    int bbase = blockIdx.x * 32;
    if (t < WIN * NCLS) wacc[t] = 0.f;
    if (t < WIN) wcnt[t] = 0.f;
    if (t == 0) gb_s = batch[bbase < n ? bbase : (n - 1)];
    __syncthreads();
    int d = bbase + (t >> 3);
    int lane4 = t & 3;
    int pr = (t >> 2) & 1;
    if (d < n) {
        unsigned p = off[d];
        unsigned c = degc[d];
        float a0 = 0.f, a1 = 0.f;
        union { unsigned u; h2v h; } cv;
        unsigned i = pr;
        for (; i + 2 < c; i += 4) {
            unsigned wA = t2h[(size_t)srcs[p + i] * 4 + lane4];
            unsigned wB = t2h[(size_t)srcs[p + i + 2] * 4 + lane4];
            cv.u = wA; a0 += (float)cv.h[0]; a1 += (float)cv.h[1];
            cv.u = wB; a0 += (float)cv.h[0]; a1 += (float)cv.h[1];
        }
        if (i < c) {
            unsigned w = t2h[(size_t)srcs[p + i] * 4 + lane4];
            cv.u = w; a0 += (float)cv.h[0]; a1 += (float)cv.h[1];
        }
        a0 += __shfl_xor(a0, 4, 64);
        a1 += __shfl_xor(a1, 4, 64);
        if (pr == 0) {
            cv.u = t2h[(size_t)d * 4 + lane4];  // self loop
            a0 += (float)cv.h[0]; a1 += (float)cv.h[1];
            float di = rsqrtf((float)(c + 1u));
            float v0 = di * a0 + b2[2 * lane4];
            float v1 = di * a1 + b2[2 * lane4 + 1];
            int g = batch[d];
            int gi = g - gb_s;
            if (gi < WIN) {
                atomicAdd(&wacc[gi * NCLS + 2 * lane4], v0);
                atomicAdd(&wacc[gi * NCLS + 2 * lane4 + 1], v1);
                if ((t & 7) == 0) atomicAdd(&wcnt[gi], 1.f);
            } else {
                atomicAdd(&out[(size_t)g * NCLS + 2 * lane4], v0);
                atomicAdd(&out[(size_t)g * NCLS + 2 * lane4 + 1], v1);
                if ((t & 7) == 0) atomicAdd(&cg[g], 1.f);
            }
        }
    }
    __syncthreads();
    if (t < WIN * NCLS && wcnt[t >> 3] > 0.f)
        atomicAdd(&out[(size_t)(gb_s + (t >> 3)) * NCLS + (t & 7)], wacc[t]);
    if (t < WIN && wcnt[t] > 0.f) atomicAdd(&cg[gb_s + t], wcnt[t]);
}

__global__ void k_div(float* __restrict__ out, const float* __restrict__ cg, int total) {
    int i = blockIdx.x * blockDim.x + threadIdx.x;
    if (i < total) out[i] /= fmaxf(cg[i / NCLS], 1.0f);
}

extern "C" void kernel_launch(void* const* d_in, const int* in_sizes, int n_in,
                              void* d_out, int out_size, void* d_ws, size_t ws_size,
                              hipStream_t stream) {
    const float* x = (const float*)d_in[0];
    const int* ei = (const int*)d_in[1];
    const int* batch = (const int*)d_in[2];
    const float* W1 = (const float*)d_in[4];
    const float* b1 = (const float*)d_in[5];
    const float* W2 = (const float*)d_in[6];
    const float* b2 = (const float*)d_in[7];

    int n = in_sizes[0] / F_IN;
    int e = in_sizes[1] / 2;
    int g = out_size / NCLS;
    const int* src = ei;
    const int* dst = ei + e;
    int nbins = (n + NPB - 1) >> BSH;  // 196 for n=100000

    char* w = (char*)d_ws;
    unsigned* binCur = (unsigned*)w; w += (size_t)MAXBINS * 4;
    unsigned* degc   = (unsigned*)w; w += (size_t)n * 4;
    unsigned* off    = (unsigned*)w; w += (size_t)n * 4;
    unsigned* t1h    = (unsigned*)w; w += (size_t)n * 8 * 4;   // fp16 pairs, 3.2 MB
    unsigned* hbuf   = (unsigned*)w; w += (size_t)n * 8 * 4;   // fp16 pairs, 3.2 MB
    unsigned* t2h    = (unsigned*)w; w += (size_t)n * 4 * 4;   // fp16 pairs, 1.6 MB
    float* cg        = (float*)w;    w += (size_t)g * 4;
    w = (char*)(((size_t)w + 255) & ~(size_t)255);
    unsigned* binbuf = (unsigned*)w; w += (size_t)nbins * BCAP * 4;  // 14.5 MB
    unsigned* srcs   = (unsigned*)w; w += (size_t)nbins * BCAP * 4;  // 14.5 MB

    hipMemsetAsync(cg, 0, (size_t)g * 4, stream);
    hipMemsetAsync(d_out, 0, (size_t)out_size * 4, stream);

    k_bininit<<<1, 256, 0, stream>>>(binCur, nbins);
    k_binA<<<(e + TILE - 1) / TILE, 256, 0, stream>>>(src, dst, e, binCur, binbuf);
    k_binB<<<nbins, 256, 0, stream>>>(binbuf, binCur, n, srcs, off, degc);
    k_gemm1<<<(n + 15) / 16, 256, 0, stream>>>(x, W1, degc, (_Float16*)t1h, n);
    k_agg1<<<(n + 15) / 16, 256, 0, stream>>>(srcs, off, degc, t1h, b1, hbuf, n);
    k_gemm2<<<(n + 255) / 256, 256, 0, stream>>>(hbuf, W2, degc, t2h, n);
    k_agg2pool<<<(n + 31) / 32, 256, 0, stream>>>(srcs, off, degc, t2h, b2, batch,
                                                  (float*)d_out, cg, n);
    k_div<<<(out_size + 255) / 256, 256, 0, stream>>>((float*)d_out, cg, out_size);
}

// Round 13
// 196.998 us; speedup vs baseline: 5.4242x; 1.1287x over previous
//
#include <hip/hip_runtime.h>

#define F_IN 256
#define HID 16
#define NCLS 8
#define BSH 9
#define NPB 512               // nodes per bin
#define MAXBINS 256
#define BCAP 18432u           // per-bin edge capacity (mean 16384, +16 sigma)
#define TILE 4096
#define WIN 8
#define GROWS 64              // gemm1 rows per block
#define APITCH 280            // fp16 pitch: banks spread, <=2-way alias on ds_read_b128

typedef float f4v __attribute__((ext_vector_type(4)));
typedef float f32x4 __attribute__((ext_vector_type(4)));
typedef _Float16 h2v __attribute__((ext_vector_type(2)));
typedef _Float16 f16x4 __attribute__((ext_vector_type(4)));
typedef _Float16 f16x8 __attribute__((ext_vector_type(8)));

// ---------- init per-bin cursors ---------------------------------------------
__global__ void k_bininit(unsigned* __restrict__ binCur, int nbins) {
    int t = threadIdx.x;
    if (t < nbins) binCur[t] = (unsigned)t * BCAP;
}

// ---------- pass A: bin edges by dst>>9 (contiguous runs, no write amp) ------
__global__ void __launch_bounds__(256) k_binA(const int* __restrict__ src,
                                              const int* __restrict__ dst, int e,
                                              unsigned* __restrict__ binCur,
                                              unsigned* __restrict__ binbuf) {
    __shared__ unsigned scnt[MAXBINS], lbase[MAXBINS], gbase[MAXBINS];
    __shared__ unsigned sbuf[TILE];
    __shared__ unsigned char sbin[TILE];
    int t = threadIdx.x;
    if (t < MAXBINS) scnt[t] = 0u;
    __syncthreads();
    int base = blockIdx.x * TILE;
    unsigned ent[16], rank[16];
    int ebin[16];
#pragma unroll
    for (int i = 0; i < 16; ++i) {
        int j = base + t + i * 256;
        ebin[i] = -1;
        if (j < e) {
            int d = __builtin_nontemporal_load(&dst[j]);
            int s = __builtin_nontemporal_load(&src[j]);
            ent[i] = ((unsigned)s << BSH) | ((unsigned)d & (NPB - 1));
            ebin[i] = d >> BSH;
            rank[i] = atomicAdd(&scnt[ebin[i]], 1u);
        }
    }
    __syncthreads();
    if (t == 0) {
        unsigned run = 0;
        for (int b = 0; b < MAXBINS; ++b) { lbase[b] = run; run += scnt[b]; }
    }
    __syncthreads();
    if (t < MAXBINS && scnt[t] > 0u) gbase[t] = atomicAdd(&binCur[t], scnt[t]);
    __syncthreads();
#pragma unroll
    for (int i = 0; i < 16; ++i)
        if (ebin[i] >= 0) {
            unsigned p = lbase[ebin[i]] + rank[i];
            sbuf[p] = ent[i];
            sbin[p] = (unsigned char)ebin[i];
        }
    __syncthreads();
    int total = e - base; if (total > TILE) total = TILE;
    for (int idx = t; idx < total; idx += 256) {
        int b = sbin[idx];
        __builtin_nontemporal_store(sbuf[idx], &binbuf[gbase[b] + ((unsigned)idx - lbase[b])]);
    }
}

// ---------- pass B: per-bin counting sort by exact dst -> CSR ----------------
__global__ void __launch_bounds__(256) k_binB(const unsigned* __restrict__ binbuf,
                                              const unsigned* __restrict__ binCur,
                                              int n,
                                              unsigned* __restrict__ srcs,
                                              unsigned* __restrict__ off,
                                              unsigned* __restrict__ degc) {
    __shared__ unsigned hist[NPB];
    __shared__ unsigned pref[NPB];
    __shared__ unsigned s1[256];
    int t = threadIdx.x;
    int b = blockIdx.x;
    unsigned base = (unsigned)b * BCAP;
    unsigned end = binCur[b];
    for (int i = t; i < NPB; i += 256) hist[i] = 0u;
    __syncthreads();
    for (unsigned j = base + t; j < end; j += 256)
        atomicAdd(&hist[__builtin_nontemporal_load(&binbuf[j]) & (NPB - 1)], 1u);
    __syncthreads();
    unsigned h0 = hist[2 * t], h1 = hist[2 * t + 1];
    unsigned pair = h0 + h1;
    s1[t] = pair;
    __syncthreads();
    for (int o = 1; o < 256; o <<= 1) {
        unsigned v = (t >= o) ? s1[t - o] : 0u;
        __syncthreads();
        s1[t] += v;
        __syncthreads();
    }
    unsigned exc = s1[t] - pair;
    pref[2 * t] = exc;
    pref[2 * t + 1] = exc + h0;
    __syncthreads();
    int dbase = b << BSH;
    for (int i = t; i < NPB; i += 256) {
        int d = dbase + i;
        if (d < n) { off[d] = base + pref[i]; degc[d] = hist[i]; }
    }
    __syncthreads();
    for (int i = t; i < NPB; i += 256) hist[i] = 0u;  // reuse as cursors
    __syncthreads();
    for (unsigned j = base + t; j < end; j += 256) {
        unsigned v = __builtin_nontemporal_load(&binbuf[j]);
        unsigned dl = v & (NPB - 1);
        unsigned r = atomicAdd(&hist[dl], 1u);
        srcs[base + pref[dl] + r] = v >> BSH;
    }
}

// ---------- GEMM1 via MFMA: t1h[n][16] fp16 = (x@W1)*rsqrt(deg+1) ------------
// W1 held in 8 B-fragments (32 VGPR); x tile fp32->fp16 staged in LDS.
__global__ void __launch_bounds__(256) k_gemm1(const float* __restrict__ x,
                                               const float* __restrict__ W1,
                                               const unsigned* __restrict__ degc,
                                               _Float16* __restrict__ t1h, int n) {
    __shared__ _Float16 xs[4][16 * APITCH];  // 4 tiles x 8960 B = 35840 B
    int t = threadIdx.x;
    int lane = t & 63;
    int wv = t >> 6;
    // B fragments: lane holds W1[kc*32 + (lane>>4)*8 + j][lane&15]
    int col = lane & 15;
    int k0 = (lane >> 4) * 8;
    f16x8 bfrag[8];
#pragma unroll
    for (int kc = 0; kc < 8; ++kc)
#pragma unroll
        for (int j = 0; j < 8; ++j)
            bfrag[kc][j] = (_Float16)W1[(kc * 32 + k0 + j) * HID + col];
    int rbase = blockIdx.x * GROWS;
    int nrows = n - rbase; if (nrows > GROWS) nrows = GROWS;
    // stage fp32 -> fp16, coalesced
#pragma unroll
    for (int it = 0; it < GROWS * 64 / 256; ++it) {
        int q = t + it * 256;           // float4 index: 64 per row
        int row = q >> 6, c4 = q & 63;
        if (row < nrows) {
            f4v v = __builtin_nontemporal_load(
                &((const f4v*)(x + (size_t)(rbase + row) * F_IN))[c4]);
            f16x4 hv;
            hv[0] = (_Float16)v[0]; hv[1] = (_Float16)v[1];
            hv[2] = (_Float16)v[2]; hv[3] = (_Float16)v[3];
            *(f16x4*)&xs[row >> 4][(row & 15) * APITCH + c4 * 4] = hv;
        }
    }
    __syncthreads();
    // each wave: one 16-row tile, 8 MFMAs over K=256
    f32x4 acc = {0.f, 0.f, 0.f, 0.f};
    const _Float16* tile = xs[wv];
    int arow = lane & 15;
#pragma unroll
    for (int kc = 0; kc < 8; ++kc) {
        f16x8 afrag = *(const f16x8*)&tile[arow * APITCH + kc * 32 + k0];
        acc = __builtin_amdgcn_mfma_f32_16x16x32_f16(afrag, bfrag[kc], acc, 0, 0, 0);
    }
    // epilogue: D col=lane&15, row=(lane>>4)*4+reg
    int r0 = (lane >> 4) * 4;
#pragma unroll
    for (int reg = 0; reg < 4; ++reg) {
        int grow = rbase + wv * 16 + r0 + reg;
        if (grow < n) {
            float v = acc[reg] * rsqrtf((float)(degc[grow] + 1u));
            t1h[(size_t)grow * HID + col] = (_Float16)v;
        }
    }
}

// ---------- conv1: CSR gather, 16 lanes/dst (8 feat-pairs x 2 edges) ---------
__global__ void __launch_bounds__(256) k_agg1(const unsigned* __restrict__ srcs,
                                              const unsigned* __restrict__ off,
                                              const unsigned* __restrict__ degc,
                                              const unsigned* __restrict__ t1h,  // u32 pairs [n*8]
                                              const float* __restrict__ b1,
                                              unsigned* __restrict__ hbuf, int n) {
    int t = threadIdx.x;
    int d = blockIdx.x * 16 + (t >> 4);
    if (d >= n) return;
    int lane8 = t & 7;
    int oct = (t >> 3) & 1;
    unsigned p = off[d];
    unsigned c = degc[d];
    float a0 = 0.f, a1 = 0.f;
    union { unsigned u; h2v h; } cv;
    unsigned i = oct;
    for (; i + 2 < c; i += 4) {
        unsigned sA = srcs[p + i];
        unsigned sB = srcs[p + i + 2];
        unsigned wA = t1h[(size_t)sA * 8 + lane8];
        unsigned wB = t1h[(size_t)sB * 8 + lane8];
        cv.u = wA; a0 += (float)cv.h[0]; a1 += (float)cv.h[1];
        cv.u = wB; a0 += (float)cv.h[0]; a1 += (float)cv.h[1];
    }
    if (i < c) {
        unsigned w = t1h[(size_t)srcs[p + i] * 8 + lane8];
        cv.u = w; a0 += (float)cv.h[0]; a1 += (float)cv.h[1];
    }
    a0 += __shfl_xor(a0, 8, 64);
    a1 += __shfl_xor(a1, 8, 64);
    if (oct == 0) {
        cv.u = t1h[(size_t)d * 8 + lane8];  // self loop
        a0 += (float)cv.h[0]; a1 += (float)cv.h[1];
        float di = rsqrtf((float)(c + 1u));
        float h0 = fmaxf(di * a0 + b1[2 * lane8], 0.f);
        float h1 = fmaxf(di * a1 + b1[2 * lane8 + 1], 0.f);
        union { unsigned u; h2v h; } pk;
        pk.h[0] = (_Float16)h0; pk.h[1] = (_Float16)h1;
        hbuf[(size_t)d * 8 + lane8] = pk.u;
    }
}

// ---------- GEMM2: t2h[n][8] fp16 = (h @ W2) * rsqrt(deg+1) ------------------
__global__ void __launch_bounds__(256) k_gemm2(const unsigned* __restrict__ hbuf,
                                               const float* __restrict__ W2,
                                               const unsigned* __restrict__ degc,
                                               unsigned* __restrict__ t2h, int n) {
    __shared__ float w2s[HID * NCLS];
    if (threadIdx.x < HID * NCLS) w2s[threadIdx.x] = W2[threadIdx.x];
    __syncthreads();
    int i = blockIdx.x * 256 + threadIdx.x;
    if (i >= n) return;
    union { uint4 q; unsigned u[4]; } A, B;
    const uint4* hb = (const uint4*)(hbuf + (size_t)i * 8);
    A.q = hb[0]; B.q = hb[1];
    float h[HID];
    union { unsigned u; h2v h; } cv;
#pragma unroll
    for (int q = 0; q < 4; ++q) {
        cv.u = A.u[q]; h[2 * q] = (float)cv.h[0]; h[2 * q + 1] = (float)cv.h[1];
        cv.u = B.u[q]; h[8 + 2 * q] = (float)cv.h[0]; h[8 + 2 * q + 1] = (float)cv.h[1];
    }
    float o[NCLS];
#pragma unroll
    for (int c = 0; c < NCLS; ++c) o[c] = 0.f;
#pragma unroll
    for (int k = 0; k < HID; ++k)
#pragma unroll
        for (int c = 0; c < NCLS; ++c) o[c] += h[k] * w2s[k * NCLS + c];
    float di = rsqrtf((float)(degc[i] + 1u));
    union { uint4 q; unsigned u[4]; } O;
#pragma unroll
    for (int q = 0; q < 4; ++q) {
        union { unsigned u; h2v h; } pk;
        pk.h[0] = (_Float16)(o[2 * q] * di);
        pk.h[1] = (_Float16)(o[2 * q + 1] * di);
        O.u[q] = pk.u;
    }
    ((uint4*)(t2h + (size_t)i * 4))[0] = O.q;
}

// ---------- conv2: CSR gather 8 lanes/dst + fused windowed mean-pool ---------
__global__ void __launch_bounds__(256) k_agg2pool(const unsigned* __restrict__ srcs,
                                                  const unsigned* __restrict__ off,
                                                  const unsigned* __restrict__ degc,
                                                  const unsigned* __restrict__ t2h,  // u32 pairs [n*4]
                                                  const float* __restrict__ b2,
                                                  const int* __restrict__ batch,
                                                  float* __restrict__ out,
                                                  float* __restrict__ cg, int n) {
    __shared__ float wacc[WIN * NCLS];
    __shared__ float wcnt[WIN];
    __shared__ int gb_s;
    int t = threadIdx.x;
    int bbase = blockIdx.x * 32;
    if (t < WIN * NCLS) wacc[t] = 0.f;
    if (t < WIN) wcnt[t] = 0.f;
    if (t == 0) gb_s = batch[bbase < n ? bbase : (n - 1)];
    __syncthreads();
    int d = bbase + (t >> 3);
    int lane4 = t & 3;
    int pr = (t >> 2) & 1;
    if (d < n) {
        unsigned p = off[d];
        unsigned c = degc[d];
        float a0 = 0.f, a1 = 0.f;
        union { unsigned u; h2v h; } cv;
        unsigned i = pr;
        for (; i + 2 < c; i += 4) {
            unsigned wA = t2h[(size_t)srcs[p + i] * 4 + lane4];
            unsigned wB = t2h[(size_t)srcs[p + i + 2] * 4 + lane4];
            cv.u = wA; a0 += (float)cv.h[0]; a1 += (float)cv.h[1];
            cv.u = wB; a0 += (float)cv.h[0]; a1 += (float)cv.h[1];
        }
        if (i < c) {
            unsigned w = t2h[(size_t)srcs[p + i] * 4 + lane4];
            cv.u = w; a0 += (float)cv.h[0]; a1 += (float)cv.h[1];
        }
        a0 += __shfl_xor(a0, 4, 64);
        a1 += __shfl_xor(a1, 4, 64);
        if (pr == 0) {
            cv.u = t2h[(size_t)d * 4 + lane4];  // self loop
            a0 += (float)cv.h[0]; a1 += (float)cv.h[1];
            float di = rsqrtf((float)(c + 1u));
            float v0 = di * a0 + b2[2 * lane4];
            float v1 = di * a1 + b2[2 * lane4 + 1];
            int g = batch[d];
            int gi = g - gb_s;
            if (gi < WIN) {
                atomicAdd(&wacc[gi * NCLS + 2 * lane4], v0);
                atomicAdd(&wacc[gi * NCLS + 2 * lane4 + 1], v1);
                if ((t & 7) == 0) atomicAdd(&wcnt[gi], 1.f);
            } else {
                atomicAdd(&out[(size_t)g * NCLS + 2 * lane4], v0);
                atomicAdd(&out[(size_t)g * NCLS + 2 * lane4 + 1], v1);
                if ((t & 7) == 0) atomicAdd(&cg[g], 1.f);
            }
        }
    }
    __syncthreads();
    if (t < WIN * NCLS && wcnt[t >> 3] > 0.f)
        atomicAdd(&out[(size_t)(gb_s + (t >> 3)) * NCLS + (t & 7)], wacc[t]);
    if (t < WIN && wcnt[t] > 0.f) atomicAdd(&cg[gb_s + t], wcnt[t]);
}

__global__ void k_div(float* __restrict__ out, const float* __restrict__ cg, int total) {
    int i = blockIdx.x * blockDim.x + threadIdx.x;
    if (i < total) out[i] /= fmaxf(cg[i / NCLS], 1.0f);
}

extern "C" void kernel_launch(void* const* d_in, const int* in_sizes, int n_in,
                              void* d_out, int out_size, void* d_ws, size_t ws_size,
                              hipStream_t stream) {
    const float* x = (const float*)d_in[0];
    const int* ei = (const int*)d_in[1];
    const int* batch = (const int*)d_in[2];
    const float* W1 = (const float*)d_in[4];
    const float* b1 = (const float*)d_in[5];
    const float* W2 = (const float*)d_in[6];
    const float* b2 = (const float*)d_in[7];

    int n = in_sizes[0] / F_IN;
    int e = in_sizes[1] / 2;
    int g = out_size / NCLS;
    const int* src = ei;
    const int* dst = ei + e;
    int nbins = (n + NPB - 1) >> BSH;  // 196 for n=100000

    char* w = (char*)d_ws;
    unsigned* binCur = (unsigned*)w; w += (size_t)MAXBINS * 4;
    unsigned* degc   = (unsigned*)w; w += (size_t)n * 4;
    unsigned* off    = (unsigned*)w; w += (size_t)n * 4;
    unsigned* t1h    = (unsigned*)w; w += (size_t)n * 8 * 4;   // fp16 pairs, 3.2 MB
    unsigned* hbuf   = (unsigned*)w; w += (size_t)n * 8 * 4;   // fp16 pairs, 3.2 MB
    unsigned* t2h    = (unsigned*)w; w += (size_t)n * 4 * 4;   // fp16 pairs, 1.6 MB
    float* cg        = (float*)w;    w += (size_t)g * 4;
    w = (char*)(((size_t)w + 255) & ~(size_t)255);
    unsigned* binbuf = (unsigned*)w; w += (size_t)nbins * BCAP * 4;  // 14.5 MB
    unsigned* srcs   = (unsigned*)w; w += (size_t)nbins * BCAP * 4;  // 14.5 MB

    hipMemsetAsync(cg, 0, (size_t)g * 4, stream);
    hipMemsetAsync(d_out, 0, (size_t)out_size * 4, stream);

    k_bininit<<<1, 256, 0, stream>>>(binCur, nbins);
    k_binA<<<(e + TILE - 1) / TILE, 256, 0, stream>>>(src, dst, e, binCur, binbuf);
    k_binB<<<nbins, 256, 0, stream>>>(binbuf, binCur, n, srcs, off, degc);
    k_gemm1<<<(n + GROWS - 1) / GROWS, 256, 0, stream>>>(x, W1, degc, (_Float16*)t1h, n);
    k_agg1<<<(n + 15) / 16, 256, 0, stream>>>(srcs, off, degc, t1h, b1, hbuf, n);
    k_gemm2<<<(n + 255) / 256, 256, 0, stream>>>(hbuf, W2, degc, t2h, n);
    k_agg2pool<<<(n + 31) / 32, 256, 0, stream>>>(srcs, off, degc, t2h, b2, batch,
                                                  (float*)d_out, cg, n);
    k_div<<<(out_size + 255) / 256, 256, 0, stream>>>((float*)d_out, cg, out_size);
}

// Round 14
// 188.122 us; speedup vs baseline: 5.6801x; 1.0472x over previous
//
#include <hip/hip_runtime.h>

#define F_IN 256
#define HID 16
#define NCLS 8
#define BSH 9
#define NPB 512               // nodes per bin
#define MAXBINS 256
#define BCAP 18432u           // per-bin edge capacity (mean 16384, +16 sigma)
#define TILE 8192             // edges per binA block (512 threads)
#define WIN 8
#define GROWS 64              // gemm1 rows per block
#define APITCH 280            // fp16 pitch: <=2-way alias on ds_read_b128

typedef float f4v __attribute__((ext_vector_type(4)));
typedef float f32x4 __attribute__((ext_vector_type(4)));
typedef _Float16 h2v __attribute__((ext_vector_type(2)));
typedef _Float16 f16x4 __attribute__((ext_vector_type(4)));
typedef _Float16 f16x8 __attribute__((ext_vector_type(8)));

// ---------- init: bin cursors + packed W1 MFMA B-fragments -------------------
__global__ void k_init(unsigned* __restrict__ binCur, int nbins,
                       const float* __restrict__ W1, _Float16* __restrict__ wfrag) {
    int t = threadIdx.x;
    if (t < nbins) binCur[t] = (unsigned)t * BCAP;
    if (t < 64) {
        int col = t & 15, k0 = (t >> 4) * 8;
#pragma unroll
        for (int kc = 0; kc < 8; ++kc) {
            f16x8 v;
#pragma unroll
            for (int j = 0; j < 8; ++j)
                v[j] = (_Float16)W1[(kc * 32 + k0 + j) * HID + col];
            *(f16x8*)&wfrag[((size_t)t * 8 + kc) * 8] = v;
        }
    }
}

// ---------- pass A: bin edges by dst>>9 (contiguous runs) --------------------
__global__ void __launch_bounds__(512) k_binA(const int* __restrict__ src,
                                              const int* __restrict__ dst, int e,
                                              unsigned* __restrict__ binCur,
                                              unsigned* __restrict__ binbuf) {
    __shared__ unsigned scnt[MAXBINS], lbase[MAXBINS], gbase[MAXBINS];
    __shared__ unsigned sbuf[TILE];
    __shared__ unsigned char sbin[TILE];
    int t = threadIdx.x;
    if (t < MAXBINS) scnt[t] = 0u;
    __syncthreads();
    int base = blockIdx.x * TILE;
    unsigned ent[16], rank[16];
    int ebin[16];
#pragma unroll
    for (int i = 0; i < 16; ++i) {
        int j = base + t + i * 512;
        ebin[i] = -1;
        if (j < e) {
            int d = __builtin_nontemporal_load(&dst[j]);
            int s = __builtin_nontemporal_load(&src[j]);
            ent[i] = ((unsigned)s << BSH) | ((unsigned)d & (NPB - 1));
            ebin[i] = d >> BSH;
            rank[i] = atomicAdd(&scnt[ebin[i]], 1u);
        }
    }
    __syncthreads();
    if (t == 0) {
        unsigned run = 0;
        for (int b = 0; b < MAXBINS; ++b) { lbase[b] = run; run += scnt[b]; }
    }
    __syncthreads();
    if (t < MAXBINS && scnt[t] > 0u) gbase[t] = atomicAdd(&binCur[t], scnt[t]);
    __syncthreads();
#pragma unroll
    for (int i = 0; i < 16; ++i)
        if (ebin[i] >= 0) {
            unsigned p = lbase[ebin[i]] + rank[i];
            sbuf[p] = ent[i];
            sbin[p] = (unsigned char)ebin[i];
        }
    __syncthreads();
    int total = e - base; if (total > TILE) total = TILE;
    for (int idx = t; idx < total; idx += 512) {
        int b = sbin[idx];
        __builtin_nontemporal_store(sbuf[idx], &binbuf[gbase[b] + ((unsigned)idx - lbase[b])]);
    }
}

// ---------- pass B: per-bin counting sort by exact dst -> CSR ----------------
__global__ void __launch_bounds__(256) k_binB(const unsigned* __restrict__ binbuf,
                                              const unsigned* __restrict__ binCur,
                                              int n,
                                              unsigned* __restrict__ srcs,
                                              unsigned* __restrict__ off,
                                              unsigned* __restrict__ degc) {
    __shared__ unsigned hist[NPB];
    __shared__ unsigned pref[NPB];
    __shared__ unsigned s1[256];
    int t = threadIdx.x;
    int b = blockIdx.x;
    unsigned base = (unsigned)b * BCAP;
    unsigned end = binCur[b];
    for (int i = t; i < NPB; i += 256) hist[i] = 0u;
    __syncthreads();
    for (unsigned j = base + t; j < end; j += 256)
        atomicAdd(&hist[__builtin_nontemporal_load(&binbuf[j]) & (NPB - 1)], 1u);
    __syncthreads();
    unsigned h0 = hist[2 * t], h1 = hist[2 * t + 1];
    unsigned pair = h0 + h1;
    s1[t] = pair;
    __syncthreads();
    for (int o = 1; o < 256; o <<= 1) {
        unsigned v = (t >= o) ? s1[t - o] : 0u;
        __syncthreads();
        s1[t] += v;
        __syncthreads();
    }
    unsigned exc = s1[t] - pair;
    pref[2 * t] = exc;
    pref[2 * t + 1] = exc + h0;
    __syncthreads();
    int dbase = b << BSH;
    for (int i = t; i < NPB; i += 256) {
        int d = dbase + i;
        if (d < n) { off[d] = base + pref[i]; degc[d] = hist[i]; }
    }
    __syncthreads();
    for (int i = t; i < NPB; i += 256) hist[i] = 0u;  // reuse as cursors
    __syncthreads();
    for (unsigned j = base + t; j < end; j += 256) {
        unsigned v = __builtin_nontemporal_load(&binbuf[j]);
        unsigned dl = v & (NPB - 1);
        unsigned r = atomicAdd(&hist[dl], 1u);
        srcs[base + pref[dl] + r] = v >> BSH;
    }
}

// ---------- GEMM1 via MFMA: t1h[n][16] fp16 = (x@W1)*rsqrt(deg+1) ------------
__global__ void __launch_bounds__(256) k_gemm1(const float* __restrict__ x,
                                               const _Float16* __restrict__ wfrag,
                                               const unsigned* __restrict__ degc,
                                               _Float16* __restrict__ t1h, int n) {
    __shared__ _Float16 xs[4][16 * APITCH];  // 35840 B
    int t = threadIdx.x;
    int lane = t & 63;
    int wv = t >> 6;
    int col = lane & 15;
    int k0 = (lane >> 4) * 8;
    f16x8 bfrag[8];
#pragma unroll
    for (int kc = 0; kc < 8; ++kc)
        bfrag[kc] = *(const f16x8*)&wfrag[((size_t)lane * 8 + kc) * 8];
    int rbase = blockIdx.x * GROWS;
    int nrows = n - rbase; if (nrows > GROWS) nrows = GROWS;
#pragma unroll
    for (int it = 0; it < GROWS * 64 / 256; ++it) {
        int q = t + it * 256;           // float4 index: 64 per row
        int row = q >> 6, c4 = q & 63;
        if (row < nrows) {
            f4v v = __builtin_nontemporal_load(
                &((const f4v*)(x + (size_t)(rbase + row) * F_IN))[c4]);
            f16x4 hv;
            hv[0] = (_Float16)v[0]; hv[1] = (_Float16)v[1];
            hv[2] = (_Float16)v[2]; hv[3] = (_Float16)v[3];
            *(f16x4*)&xs[row >> 4][(row & 15) * APITCH + c4 * 4] = hv;
        }
    }
    __syncthreads();
    f32x4 acc = {0.f, 0.f, 0.f, 0.f};
    const _Float16* tile = xs[wv];
    int arow = lane & 15;
#pragma unroll
    for (int kc = 0; kc < 8; ++kc) {
        f16x8 afrag = *(const f16x8*)&tile[arow * APITCH + kc * 32 + k0];
        acc = __builtin_amdgcn_mfma_f32_16x16x32_f16(afrag, bfrag[kc], acc, 0, 0, 0);
    }
    int r0 = (lane >> 4) * 4;
#pragma unroll
    for (int reg = 0; reg < 4; ++reg) {
        int grow = rbase + wv * 16 + r0 + reg;
        if (grow < n) {
            float v = acc[reg] * rsqrtf((float)(degc[grow] + 1u));
            t1h[(size_t)grow * HID + col] = (_Float16)v;
        }
    }
}

// ---------- conv1: CSR gather, 16 lanes/dst, 4 edges in flight per oct -------
__global__ void __launch_bounds__(256) k_agg1(const unsigned* __restrict__ srcs,
                                              const unsigned* __restrict__ off,
                                              const unsigned* __restrict__ degc,
                                              const unsigned* __restrict__ t1h,  // u32 pairs [n*8]
                                              const float* __restrict__ b1,
                                              unsigned* __restrict__ hbuf, int n) {
    int t = threadIdx.x;
    int d = blockIdx.x * 16 + (t >> 4);
    if (d >= n) return;
    int lane8 = t & 7;
    int oct = (t >> 3) & 1;
    unsigned p = off[d];
    unsigned c = degc[d];
    float a0 = 0.f, a1 = 0.f;
    union { unsigned u; h2v h; } cv;
    unsigned i = oct;
    for (; i + 6 < c; i += 8) {
        unsigned s0 = srcs[p + i],     s1 = srcs[p + i + 2];
        unsigned s2 = srcs[p + i + 4], s3 = srcs[p + i + 6];
        unsigned w0 = t1h[(size_t)s0 * 8 + lane8];
        unsigned w1 = t1h[(size_t)s1 * 8 + lane8];
        unsigned w2 = t1h[(size_t)s2 * 8 + lane8];
        unsigned w3 = t1h[(size_t)s3 * 8 + lane8];
        cv.u = w0; a0 += (float)cv.h[0]; a1 += (float)cv.h[1];
        cv.u = w1; a0 += (float)cv.h[0]; a1 += (float)cv.h[1];
        cv.u = w2; a0 += (float)cv.h[0]; a1 += (float)cv.h[1];
        cv.u = w3; a0 += (float)cv.h[0]; a1 += (float)cv.h[1];
    }
    for (; i + 2 < c; i += 4) {
        unsigned s0 = srcs[p + i], s1 = srcs[p + i + 2];
        unsigned w0 = t1h[(size_t)s0 * 8 + lane8];
        unsigned w1 = t1h[(size_t)s1 * 8 + lane8];
        cv.u = w0; a0 += (float)cv.h[0]; a1 += (float)cv.h[1];
        cv.u = w1; a0 += (float)cv.h[0]; a1 += (float)cv.h[1];
    }
    if (i < c) {
        unsigned w = t1h[(size_t)srcs[p + i] * 8 + lane8];
        cv.u = w; a0 += (float)cv.h[0]; a1 += (float)cv.h[1];
    }
    a0 += __shfl_xor(a0, 8, 64);
    a1 += __shfl_xor(a1, 8, 64);
    if (oct == 0) {
        cv.u = t1h[(size_t)d * 8 + lane8];  // self loop
        a0 += (float)cv.h[0]; a1 += (float)cv.h[1];
        float di = rsqrtf((float)(c + 1u));
        float h0 = fmaxf(di * a0 + b1[2 * lane8], 0.f);
        float h1 = fmaxf(di * a1 + b1[2 * lane8 + 1], 0.f);
        union { unsigned u; h2v h; } pk;
        pk.h[0] = (_Float16)h0; pk.h[1] = (_Float16)h1;
        hbuf[(size_t)d * 8 + lane8] = pk.u;
    }
}

// ---------- GEMM2: t2h[n][8] fp16 = (h @ W2) * rsqrt(deg+1) ------------------
__global__ void __launch_bounds__(256) k_gemm2(const unsigned* __restrict__ hbuf,
                                               const float* __restrict__ W2,
                                               const unsigned* __restrict__ degc,
                                               unsigned* __restrict__ t2h, int n) {
    __shared__ float w2s[HID * NCLS];
    if (threadIdx.x < HID * NCLS) w2s[threadIdx.x] = W2[threadIdx.x];
    __syncthreads();
    int i = blockIdx.x * 256 + threadIdx.x;
    if (i >= n) return;
    union { uint4 q; unsigned u[4]; } A, B;
    const uint4* hb = (const uint4*)(hbuf + (size_t)i * 8);
    A.q = hb[0]; B.q = hb[1];
    float h[HID];
    union { unsigned u; h2v h; } cv;
#pragma unroll
    for (int q = 0; q < 4; ++q) {
        cv.u = A.u[q]; h[2 * q] = (float)cv.h[0]; h[2 * q + 1] = (float)cv.h[1];
        cv.u = B.u[q]; h[8 + 2 * q] = (float)cv.h[0]; h[8 + 2 * q + 1] = (float)cv.h[1];
    }
    float o[NCLS];
#pragma unroll
    for (int c = 0; c < NCLS; ++c) o[c] = 0.f;
#pragma unroll
    for (int k = 0; k < HID; ++k)
#pragma unroll
        for (int c = 0; c < NCLS; ++c) o[c] += h[k] * w2s[k * NCLS + c];
    float di = rsqrtf((float)(degc[i] + 1u));
    union { uint4 q; unsigned u[4]; } O;
#pragma unroll
    for (int q = 0; q < 4; ++q) {
        union { unsigned u; h2v h; } pk;
        pk.h[0] = (_Float16)(o[2 * q] * di);
        pk.h[1] = (_Float16)(o[2 * q + 1] * di);
        O.u[q] = pk.u;
    }
    ((uint4*)(t2h + (size_t)i * 4))[0] = O.q;
}

// ---------- conv2: CSR gather 8 lanes/dst, 4-deep, fused mean-pool -----------
__global__ void __launch_bounds__(256) k_agg2pool(const unsigned* __restrict__ srcs,
                                                  const unsigned* __restrict__ off,
                                                  const unsigned* __restrict__ degc,
                                                  const unsigned* __restrict__ t2h,  // u32 pairs [n*4]
                                                  const float* __restrict__ b2,
                                                  const int* __restrict__ batch,
                                                  float* __restrict__ out,
                                                  float* __restrict__ cg, int n) {
    __shared__ float wacc[WIN * NCLS];
    __shared__ float wcnt[WIN];
    __shared__ int gb_s;
    int t = threadIdx.x;
    int bbase = blockIdx.x * 32;
    if (t < WIN * NCLS) wacc[t] = 0.f;
    if (t < WIN) wcnt[t] = 0.f;
    if (t == 0) gb_s = batch[bbase < n ? bbase : (n - 1)];
    __syncthreads();
    int d = bbase + (t >> 3);
    int lane4 = t & 3;
    int pr = (t >> 2) & 1;
    if (d < n) {
        unsigned p = off[d];
        unsigned c = degc[d];
        float a0 = 0.f, a1 = 0.f;
        union { unsigned u; h2v h; } cv;
        unsigned i = pr;
        for (; i + 6 < c; i += 8) {
            unsigned w0 = t2h[(size_t)srcs[p + i] * 4 + lane4];
            unsigned w1 = t2h[(size_t)srcs[p + i + 2] * 4 + lane4];
            unsigned w2 = t2h[(size_t)srcs[p + i + 4] * 4 + lane4];
            unsigned w3 = t2h[(size_t)srcs[p + i + 6] * 4 + lane4];
            cv.u = w0; a0 += (float)cv.h[0]; a1 += (float)cv.h[1];
            cv.u = w1; a0 += (float)cv.h[0]; a1 += (float)cv.h[1];
            cv.u = w2; a0 += (float)cv.h[0]; a1 += (float)cv.h[1];
            cv.u = w3; a0 += (float)cv.h[0]; a1 += (float)cv.h[1];
        }
        for (; i + 2 < c; i += 4) {
            unsigned w0 = t2h[(size_t)srcs[p + i] * 4 + lane4];
            unsigned w1 = t2h[(size_t)srcs[p + i + 2] * 4 + lane4];
            cv.u = w0; a0 += (float)cv.h[0]; a1 += (float)cv.h[1];
            cv.u = w1; a0 += (float)cv.h[0]; a1 += (float)cv.h[1];
        }
        if (i < c) {
            unsigned w = t2h[(size_t)srcs[p + i] * 4 + lane4];
            cv.u = w; a0 += (float)cv.h[0]; a1 += (float)cv.h[1];
        }
        a0 += __shfl_xor(a0, 4, 64);
        a1 += __shfl_xor(a1, 4, 64);
        if (pr == 0) {
            cv.u = t2h[(size_t)d * 4 + lane4];  // self loop
            a0 += (float)cv.h[0]; a1 += (float)cv.h[1];
            float di = rsqrtf((float)(c + 1u));
            float v0 = di * a0 + b2[2 * lane4];
            float v1 = di * a1 + b2[2 * lane4 + 1];
            int g = batch[d];
            int gi = g - gb_s;
            if (gi < WIN) {
                atomicAdd(&wacc[gi * NCLS + 2 * lane4], v0);
                atomicAdd(&wacc[gi * NCLS + 2 * lane4 + 1], v1);
                if ((t & 7) == 0) atomicAdd(&wcnt[gi], 1.f);
            } else {
                atomicAdd(&out[(size_t)g * NCLS + 2 * lane4], v0);
                atomicAdd(&out[(size_t)g * NCLS + 2 * lane4 + 1], v1);
                if ((t & 7) == 0) atomicAdd(&cg[g], 1.f);
            }
        }
    }
    __syncthreads();
    if (t < WIN * NCLS && wcnt[t >> 3] > 0.f)
        atomicAdd(&out[(size_t)(gb_s + (t >> 3)) * NCLS + (t & 7)], wacc[t]);
    if (t < WIN && wcnt[t] > 0.f) atomicAdd(&cg[gb_s + t], wcnt[t]);
}

__global__ void k_div(float* __restrict__ out, const float* __restrict__ cg, int total) {
    int i = blockIdx.x * blockDim.x + threadIdx.x;
    if (i < total) out[i] /= fmaxf(cg[i / NCLS], 1.0f);
}

extern "C" void kernel_launch(void* const* d_in, const int* in_sizes, int n_in,
                              void* d_out, int out_size, void* d_ws, size_t ws_size,
                              hipStream_t stream) {
    const float* x = (const float*)d_in[0];
    const int* ei = (const int*)d_in[1];
    const int* batch = (const int*)d_in[2];
    const float* W1 = (const float*)d_in[4];
    const float* b1 = (const float*)d_in[5];
    const float* W2 = (const float*)d_in[6];
    const float* b2 = (const float*)d_in[7];

    int n = in_sizes[0] / F_IN;
    int e = in_sizes[1] / 2;
    int g = out_size / NCLS;
    const int* src = ei;
    const int* dst = ei + e;
    int nbins = (n + NPB - 1) >> BSH;  // 196 for n=100000

    char* w = (char*)d_ws;
    unsigned* binCur = (unsigned*)w; w += (size_t)MAXBINS * 4;
    unsigned* degc   = (unsigned*)w; w += (size_t)n * 4;
    unsigned* off    = (unsigned*)w; w += (size_t)n * 4;
    unsigned* t1h    = (unsigned*)w; w += (size_t)n * 8 * 4;   // fp16 pairs, 3.2 MB
    unsigned* hbuf   = (unsigned*)w; w += (size_t)n * 8 * 4;   // fp16 pairs, 3.2 MB
    unsigned* t2h    = (unsigned*)w; w += (size_t)n * 4 * 4;   // fp16 pairs, 1.6 MB
    _Float16* wfrag  = (_Float16*)w; w += (size_t)64 * 8 * 8 * 2;  // 8 KB
    float* cg        = (float*)w;    w += (size_t)g * 4;
    w = (char*)(((size_t)w + 255) & ~(size_t)255);
    unsigned* binbuf = (unsigned*)w; w += (size_t)nbins * BCAP * 4;  // 14.5 MB
    unsigned* srcs   = (unsigned*)w; w += (size_t)nbins * BCAP * 4;  // 14.5 MB

    hipMemsetAsync(cg, 0, (size_t)g * 4, stream);
    hipMemsetAsync(d_out, 0, (size_t)out_size * 4, stream);

    k_init<<<1, 256, 0, stream>>>(binCur, nbins, W1, wfrag);
    k_binA<<<(e + TILE - 1) / TILE, 512, 0, stream>>>(src, dst, e, binCur, binbuf);
    k_binB<<<nbins, 256, 0, stream>>>(binbuf, binCur, n, srcs, off, degc);
    k_gemm1<<<(n + GROWS - 1) / GROWS, 256, 0, stream>>>(x, wfrag, degc, (_Float16*)t1h, n);
    k_agg1<<<(n + 15) / 16, 256, 0, stream>>>(srcs, off, degc, t1h, b1, hbuf, n);
    k_gemm2<<<(n + 255) / 256, 256, 0, stream>>>(hbuf, W2, degc, t2h, n);
    k_agg2pool<<<(n + 31) / 32, 256, 0, stream>>>(srcs, off, degc, t2h, b2, batch,
                                                  (float*)d_out, cg, n);
    k_div<<<(out_size + 255) / 256, 256, 0, stream>>>((float*)d_out, cg, out_size);
}

// Round 17
// 183.998 us; speedup vs baseline: 5.8074x; 1.0224x over previous
//
#include <hip/hip_runtime.h>

#define F_IN 256
#define HID 16
#define NCLS 8
#define BSH 9
#define NPB 512               // nodes per bin
#define MAXBINS 256
#define BCAP 18432u           // per-bin edge capacity (mean 16384, +16 sigma)
#define TILE 8192             // edges per binA block (512 threads)
#define WIN 8
#define GROWS 64              // gemm1 rows per block
#define APITCH 280            // fp16 pitch: <=2-way alias on ds_read_b128

typedef float f4v __attribute__((ext_vector_type(4)));
typedef float f32x4 __attribute__((ext_vector_type(4)));
typedef _Float16 h2v __attribute__((ext_vector_type(2)));
typedef _Float16 f16x4 __attribute__((ext_vector_type(4)));
typedef _Float16 f16x8 __attribute__((ext_vector_type(8)));

// ---------- init: bin cursors + packed W1 B-fragments + zero cg/out ----------
__global__ void k_init(unsigned* __restrict__ binCur, int nbins,
                       const float* __restrict__ W1, _Float16* __restrict__ wfrag,
                       float* __restrict__ cg, int g,
                       float* __restrict__ out, int osz) {
    int t = threadIdx.x;
    if (t < nbins) binCur[t] = (unsigned)t * BCAP;
    if (t < 64) {
        int col = t & 15, k0 = (t >> 4) * 8;
#pragma unroll
        for (int kc = 0; kc < 8; ++kc) {
            f16x8 v;
#pragma unroll
            for (int j = 0; j < 8; ++j)
                v[j] = (_Float16)W1[(kc * 32 + k0 + j) * HID + col];
            *(f16x8*)&wfrag[((size_t)t * 8 + kc) * 8] = v;
        }
    }
    for (int i = t; i < g; i += 256) cg[i] = 0.f;
    for (int i = t; i < osz; i += 256) out[i] = 0.f;
}

// ---------- pass A: bin edges by dst>>9 (contiguous runs) --------------------
__global__ void __launch_bounds__(512) k_binA(const int* __restrict__ src,
                                              const int* __restrict__ dst, int e,
                                              unsigned* __restrict__ binCur,
                                              unsigned* __restrict__ binbuf) {
    __shared__ unsigned scnt[MAXBINS], lbase[MAXBINS], gbase[MAXBINS];
    __shared__ unsigned sbuf[TILE];
    __shared__ unsigned char sbin[TILE];
    int t = threadIdx.x;
    if (t < MAXBINS) scnt[t] = 0u;
    __syncthreads();
    int base = blockIdx.x * TILE;
    unsigned ent[16], rank[16];
    int ebin[16];
#pragma unroll
    for (int i = 0; i < 16; ++i) {
        int j = base + t + i * 512;
        ebin[i] = -1;
        if (j < e) {
            int d = __builtin_nontemporal_load(&dst[j]);
            int s = __builtin_nontemporal_load(&src[j]);
            ent[i] = ((unsigned)s << BSH) | ((unsigned)d & (NPB - 1));
            ebin[i] = d >> BSH;
            rank[i] = atomicAdd(&scnt[ebin[i]], 1u);
        }
    }
    __syncthreads();
    if (t == 0) {
        unsigned run = 0;
        for (int b = 0; b < MAXBINS; ++b) { lbase[b] = run; run += scnt[b]; }
    }
    __syncthreads();
    if (t < MAXBINS && scnt[t] > 0u) gbase[t] = atomicAdd(&binCur[t], scnt[t]);
    __syncthreads();
#pragma unroll
    for (int i = 0; i < 16; ++i)
        if (ebin[i] >= 0) {
            unsigned p = lbase[ebin[i]] + rank[i];
            sbuf[p] = ent[i];
            sbin[p] = (unsigned char)ebin[i];
        }
    __syncthreads();
    int total = e - base; if (total > TILE) total = TILE;
    for (int idx = t; idx < total; idx += 512) {
        int b = sbin[idx];
        __builtin_nontemporal_store(sbuf[idx], &binbuf[gbase[b] + ((unsigned)idx - lbase[b])]);
    }
}

// ---------- pass B: per-bin counting sort by exact dst -> CSR ----------------
__global__ void __launch_bounds__(256) k_binB(const unsigned* __restrict__ binbuf,
                                              const unsigned* __restrict__ binCur,
                                              int n,
                                              unsigned* __restrict__ srcs,
                                              unsigned* __restrict__ off,
                                              unsigned* __restrict__ degc) {
    __shared__ unsigned hist[NPB];
    __shared__ unsigned pref[NPB];
    __shared__ unsigned s1[256];
    int t = threadIdx.x;
    int b = blockIdx.x;
    unsigned base = (unsigned)b * BCAP;
    unsigned end = binCur[b];
    for (int i = t; i < NPB; i += 256) hist[i] = 0u;
    __syncthreads();
    for (unsigned j = base + t; j < end; j += 256)
        atomicAdd(&hist[__builtin_nontemporal_load(&binbuf[j]) & (NPB - 1)], 1u);
    __syncthreads();
    unsigned h0 = hist[2 * t], h1 = hist[2 * t + 1];
    unsigned pair = h0 + h1;
    s1[t] = pair;
    __syncthreads();
    for (int o = 1; o < 256; o <<= 1) {
        unsigned v = (t >= o) ? s1[t - o] : 0u;
        __syncthreads();
        s1[t] += v;
        __syncthreads();
    }
    unsigned exc = s1[t] - pair;
    pref[2 * t] = exc;
    pref[2 * t + 1] = exc + h0;
    __syncthreads();
    int dbase = b << BSH;
    for (int i = t; i < NPB; i += 256) {
        int d = dbase + i;
        if (d < n) { off[d] = base + pref[i]; degc[d] = hist[i]; }
    }
    __syncthreads();
    for (int i = t; i < NPB; i += 256) hist[i] = 0u;  // reuse as cursors
    __syncthreads();
    for (unsigned j = base + t; j < end; j += 256) {
        unsigned v = __builtin_nontemporal_load(&binbuf[j]);
        unsigned dl = v & (NPB - 1);
        unsigned r = atomicAdd(&hist[dl], 1u);
        srcs[base + pref[dl] + r] = v >> BSH;
    }
}

// ---------- GEMM1 via MFMA: t1h[n][16] fp16 = (x@W1)*rsqrt(deg+1) ------------
__global__ void __launch_bounds__(256) k_gemm1(const float* __restrict__ x,
                                               const _Float16* __restrict__ wfrag,
                                               const unsigned* __restrict__ degc,
                                               _Float16* __restrict__ t1h, int n) {
    __shared__ _Float16 xs[4][16 * APITCH];  // 35840 B
    int t = threadIdx.x;
    int lane = t & 63;
    int wv = t >> 6;
    int col = lane & 15;
    int k0 = (lane >> 4) * 8;
    f16x8 bfrag[8];
#pragma unroll
    for (int kc = 0; kc < 8; ++kc)
        bfrag[kc] = *(const f16x8*)&wfrag[((size_t)lane * 8 + kc) * 8];
    int rbase = blockIdx.x * GROWS;
    int nrows = n - rbase; if (nrows > GROWS) nrows = GROWS;
#pragma unroll
    for (int it = 0; it < GROWS * 64 / 256; ++it) {
        int q = t + it * 256;           // float4 index: 64 per row
        int row = q >> 6, c4 = q & 63;
        if (row < nrows) {
            f4v v = __builtin_nontemporal_load(
                &((const f4v*)(x + (size_t)(rbase + row) * F_IN))[c4]);
            f16x4 hv;
            hv[0] = (_Float16)v[0]; hv[1] = (_Float16)v[1];
            hv[2] = (_Float16)v[2]; hv[3] = (_Float16)v[3];
            *(f16x4*)&xs[row >> 4][(row & 15) * APITCH + c4 * 4] = hv;
        }
    }
    __syncthreads();
    f32x4 acc = {0.f, 0.f, 0.f, 0.f};
    const _Float16* tile = xs[wv];
    int arow = lane & 15;
#pragma unroll
    for (int kc = 0; kc < 8; ++kc) {
        f16x8 afrag = *(const f16x8*)&tile[arow * APITCH + kc * 32 + k0];
        acc = __builtin_amdgcn_mfma_f32_16x16x32_f16(afrag, bfrag[kc], acc, 0, 0, 0);
    }
    int r0 = (lane >> 4) * 4;
#pragma unroll
    for (int reg = 0; reg < 4; ++reg) {
        int grow = rbase + wv * 16 + r0 + reg;
        if (grow < n) {
            float v = acc[reg] * rsqrtf((float)(degc[grow] + 1u));
            t1h[(size_t)grow * HID + col] = (_Float16)v;
        }
    }
}

// ---------- conv1 + GEMM2 fused: CSR gather 16 lanes/dst, shuffle-GEMM -------
__global__ void __launch_bounds__(256) k_agg1g2(const unsigned* __restrict__ srcs,
                                                const unsigned* __restrict__ off,
                                                const unsigned* __restrict__ degc,
                                                const unsigned* __restrict__ t1h,  // u32 pairs [n*8]
                                                const float* __restrict__ b1,
                                                const float* __restrict__ W2,
                                                unsigned* __restrict__ t2h, int n) {
    __shared__ float w2s[HID * NCLS];
    __shared__ float b1s[HID];
    int t = threadIdx.x;
    if (t < HID * NCLS) w2s[t] = W2[t];
    if (t < HID) b1s[t] = b1[t];
    __syncthreads();
    int d = blockIdx.x * 16 + (t >> 4);
    if (d >= n) return;
    int lane8 = t & 7;
    int oct = (t >> 3) & 1;
    unsigned p = off[d];
    unsigned c = degc[d];
    float a0 = 0.f, a1 = 0.f;
    union { unsigned u; h2v h; } cv;
    unsigned i = oct;
    for (; i + 6 < c; i += 8) {
        unsigned s0 = srcs[p + i],     s1 = srcs[p + i + 2];
        unsigned s2 = srcs[p + i + 4], s3 = srcs[p + i + 6];
        unsigned w0 = t1h[(size_t)s0 * 8 + lane8];
        unsigned w1 = t1h[(size_t)s1 * 8 + lane8];
        unsigned w2 = t1h[(size_t)s2 * 8 + lane8];
        unsigned w3 = t1h[(size_t)s3 * 8 + lane8];
        cv.u = w0; a0 += (float)cv.h[0]; a1 += (float)cv.h[1];
        cv.u = w1; a0 += (float)cv.h[0]; a1 += (float)cv.h[1];
        cv.u = w2; a0 += (float)cv.h[0]; a1 += (float)cv.h[1];
        cv.u = w3; a0 += (float)cv.h[0]; a1 += (float)cv.h[1];
    }
    for (; i + 2 < c; i += 4) {
        unsigned s0 = srcs[p + i], s1 = srcs[p + i + 2];
        unsigned w0 = t1h[(size_t)s0 * 8 + lane8];
        unsigned w1 = t1h[(size_t)s1 * 8 + lane8];
        cv.u = w0; a0 += (float)cv.h[0]; a1 += (float)cv.h[1];
        cv.u = w1; a0 += (float)cv.h[0]; a1 += (float)cv.h[1];
    }
    if (i < c) {
        unsigned w = t1h[(size_t)srcs[p + i] * 8 + lane8];
        cv.u = w; a0 += (float)cv.h[0]; a1 += (float)cv.h[1];
    }
    a0 += __shfl_xor(a0, 8, 64);
    a1 += __shfl_xor(a1, 8, 64);
    if (oct != 0) return;
    cv.u = t1h[(size_t)d * 8 + lane8];  // self loop
    a0 += (float)cv.h[0]; a1 += (float)cv.h[1];
    float di = rsqrtf((float)(c + 1u));
    float h0 = fmaxf(di * a0 + b1s[2 * lane8], 0.f);
    float h1 = fmaxf(di * a1 + b1s[2 * lane8 + 1], 0.f);
    // GEMM2 partials: this lane covers k = 2*lane8, 2*lane8+1
    float o[NCLS];
#pragma unroll
    for (int cc = 0; cc < NCLS; ++cc)
        o[cc] = h0 * w2s[(2 * lane8) * NCLS + cc] + h1 * w2s[(2 * lane8 + 1) * NCLS + cc];
    // butterfly reduce over the 8-lane group
#pragma unroll
    for (int m = 1; m < 8; m <<= 1)
#pragma unroll
        for (int cc = 0; cc < NCLS; ++cc)
            o[cc] += __shfl_xor(o[cc], m, 64);
    if (lane8 < 4) {
        union { unsigned u; h2v h; } pk;
        pk.h[0] = (_Float16)(o[2 * lane8] * di);
        pk.h[1] = (_Float16)(o[2 * lane8 + 1] * di);
        t2h[(size_t)d * 4 + lane8] = pk.u;
    }
}

// ---------- conv2: CSR gather 8 lanes/dst, 4-deep, fused mean-pool -----------
__global__ void __launch_bounds__(256) k_agg2pool(const unsigned* __restrict__ srcs,
                                                  const unsigned* __restrict__ off,
                                                  const unsigned* __restrict__ degc,
                                                  const unsigned* __restrict__ t2h,  // u32 pairs [n*4]
                                                  const float* __restrict__ b2,
                                                  const int* __restrict__ batch,
                                                  float* __restrict__ out,
                                                  float* __restrict__ cg, int n) {
    __shared__ float wacc[WIN * NCLS];
    __shared__ float wcnt[WIN];
    __shared__ int gb_s;
    int t = threadIdx.x;
    int bbase = blockIdx.x * 32;
    if (t < WIN * NCLS) wacc[t] = 0.f;
    if (t < WIN) wcnt[t] = 0.f;
    if (t == 0) gb_s = batch[bbase < n ? bbase : (n - 1)];
    __syncthreads();
    int d = bbase + (t >> 3);
    int lane4 = t & 3;
    int pr = (t >> 2) & 1;
    if (d < n) {
        unsigned p = off[d];
        unsigned c = degc[d];
        float a0 = 0.f, a1 = 0.f;
        union { unsigned u; h2v h; } cv;
        unsigned i = pr;
        for (; i + 6 < c; i += 8) {
            unsigned w0 = t2h[(size_t)srcs[p + i] * 4 + lane4];
            unsigned w1 = t2h[(size_t)srcs[p + i + 2] * 4 + lane4];
            unsigned w2 = t2h[(size_t)srcs[p + i + 4] * 4 + lane4];
            unsigned w3 = t2h[(size_t)srcs[p + i + 6] * 4 + lane4];
            cv.u = w0; a0 += (float)cv.h[0]; a1 += (float)cv.h[1];
            cv.u = w1; a0 += (float)cv.h[0]; a1 += (float)cv.h[1];
            cv.u = w2; a0 += (float)cv.h[0]; a1 += (float)cv.h[1];
            cv.u = w3; a0 += (float)cv.h[0]; a1 += (float)cv.h[1];
        }
        for (; i + 2 < c; i += 4) {
            unsigned w0 = t2h[(size_t)srcs[p + i] * 4 + lane4];
            unsigned w1 = t2h[(size_t)srcs[p + i + 2] * 4 + lane4];
            cv.u = w0; a0 += (float)cv.h[0]; a1 += (float)cv.h[1];
            cv.u = w1; a0 += (float)cv.h[0]; a1 += (float)cv.h[1];
        }
        if (i < c) {
            unsigned w = t2h[(size_t)srcs[p + i] * 4 + lane4];
            cv.u = w; a0 += (float)cv.h[0]; a1 += (float)cv.h[1];
        }
        a0 += __shfl_xor(a0, 4, 64);
        a1 += __shfl_xor(a1, 4, 64);
        if (pr == 0) {
            cv.u = t2h[(size_t)d * 4 + lane4];  // self loop
            a0 += (float)cv.h[0]; a1 += (float)cv.h[1];
            float di = rsqrtf((float)(c + 1u));
            float v0 = di * a0 + b2[2 * lane4];
            float v1 = di * a1 + b2[2 * lane4 + 1];
            int g = batch[d];
            int gi = g - gb_s;
            if (gi < WIN) {
                atomicAdd(&wacc[gi * NCLS + 2 * lane4], v0);
                atomicAdd(&wacc[gi * NCLS + 2 * lane4 + 1], v1);
                if ((t & 7) == 0) atomicAdd(&wcnt[gi], 1.f);
            } else {
                atomicAdd(&out[(size_t)g * NCLS + 2 * lane4], v0);
                atomicAdd(&out[(size_t)g * NCLS + 2 * lane4 + 1], v1);
                if ((t & 7) == 0) atomicAdd(&cg[g], 1.f);
            }
        }
    }
    __syncthreads();
    if (t < WIN * NCLS && wcnt[t >> 3] > 0.f)
        atomicAdd(&out[(size_t)(gb_s + (t >> 3)) * NCLS + (t & 7)], wacc[t]);
    if (t < WIN && wcnt[t] > 0.f) atomicAdd(&cg[gb_s + t], wcnt[t]);
}

__global__ void k_div(float* __restrict__ out, const float* __restrict__ cg, int total) {
    int i = blockIdx.x * blockDim.x + threadIdx.x;
    if (i < total) out[i] /= fmaxf(cg[i / NCLS], 1.0f);
}

extern "C" void kernel_launch(void* const* d_in, const int* in_sizes, int n_in,
                              void* d_out, int out_size, void* d_ws, size_t ws_size,
                              hipStream_t stream) {
    const float* x = (const float*)d_in[0];
    const int* ei = (const int*)d_in[1];
    const int* batch = (const int*)d_in[2];
    const float* W1 = (const float*)d_in[4];
    const float* b1 = (const float*)d_in[5];
    const float* W2 = (const float*)d_in[6];
    const float* b2 = (const float*)d_in[7];

    int n = in_sizes[0] / F_IN;
    int e = in_sizes[1] / 2;
    int g = out_size / NCLS;
    const int* src = ei;
    const int* dst = ei + e;
    int nbins = (n + NPB - 1) >> BSH;  // 196 for n=100000

    char* w = (char*)d_ws;
    unsigned* binCur = (unsigned*)w; w += (size_t)MAXBINS * 4;
    unsigned* degc   = (unsigned*)w; w += (size_t)n * 4;
    unsigned* off    = (unsigned*)w; w += (size_t)n * 4;
    unsigned* t1h    = (unsigned*)w; w += (size_t)n * 8 * 4;   // fp16 pairs, 3.2 MB
    unsigned* t2h    = (unsigned*)w; w += (size_t)n * 4 * 4;   // fp16 pairs, 1.6 MB
    _Float16* wfrag  = (_Float16*)w; w += (size_t)64 * 8 * 8 * 2;  // 8 KB
    float* cg        = (float*)w;    w += (size_t)g * 4;
    w = (char*)(((size_t)w + 255) & ~(size_t)255);
    unsigned* binbuf = (unsigned*)w; w += (size_t)nbins * BCAP * 4;  // 14.5 MB
    unsigned* srcs   = (unsigned*)w; w += (size_t)nbins * BCAP * 4;  // 14.5 MB

    k_init<<<1, 256, 0, stream>>>(binCur, nbins, W1, wfrag, cg, g, (float*)d_out, out_size);
    k_binA<<<(e + TILE - 1) / TILE, 512, 0, stream>>>(src, dst, e, binCur, binbuf);
    k_binB<<<nbins, 256, 0, stream>>>(binbuf, binCur, n, srcs, off, degc);
    k_gemm1<<<(n + GROWS - 1) / GROWS, 256, 0, stream>>>(x, wfrag, degc, (_Float16*)t1h, n);
    k_agg1g2<<<(n + 15) / 16, 256, 0, stream>>>(srcs, off, degc, t1h, b1, W2, t2h, n);
    k_agg2pool<<<(n + 31) / 32, 256, 0, stream>>>(srcs, off, degc, t2h, b2, batch,
                                                  (float*)d_out, cg, n);
    k_div<<<(out_size + 255) / 256, 256, 0, stream>>>((float*)d_out, cg, out_size);
}

// Round 19
// 179.089 us; speedup vs baseline: 5.9666x; 1.0274x over previous
//
#include <hip/hip_runtime.h>

#define F_IN 256
#define HID 16
#define NCLS 8
#define BSH 9
#define NPB 512               // nodes per bin
#define MAXBINS 256
#define BCAP 18432u           // per-bin edge capacity (mean 16384, +16 sigma)
#define TILE 8192             // edges per binA block (512 threads)
#define WIN 8
#define GROWS 64              // gemm1 rows per block
#define APITCH 280            // fp16 pitch: <=2-way alias on ds_read_b128

typedef float f4v __attribute__((ext_vector_type(4)));
typedef float f32x4 __attribute__((ext_vector_type(4)));
typedef _Float16 h2v __attribute__((ext_vector_type(2)));
typedef _Float16 f16x4 __attribute__((ext_vector_type(4)));
typedef _Float16 f16x8 __attribute__((ext_vector_type(8)));

// ---------- init: bin cursors + packed W1 B-fragments + zero cg/out ----------
__global__ void k_init(unsigned* __restrict__ binCur, int nbins,
                       const float* __restrict__ W1, _Float16* __restrict__ wfrag,
                       float* __restrict__ cg, int g,
                       float* __restrict__ out, int osz) {
    int t = threadIdx.x;
    if (t < nbins) binCur[t] = (unsigned)t * BCAP;
    if (t < 64) {
        int col = t & 15, k0 = (t >> 4) * 8;
#pragma unroll
        for (int kc = 0; kc < 8; ++kc) {
            f16x8 v;
#pragma unroll
            for (int j = 0; j < 8; ++j)
                v[j] = (_Float16)W1[(kc * 32 + k0 + j) * HID + col];
            *(f16x8*)&wfrag[((size_t)t * 8 + kc) * 8] = v;
        }
    }
    for (int i = t; i < g; i += 256) cg[i] = 0.f;
    for (int i = t; i < osz; i += 256) out[i] = 0.f;
}

// ---------- pass A: bin edges by dst>>9 (contiguous runs) --------------------
__global__ void __launch_bounds__(512) k_binA(const int* __restrict__ src,
                                              const int* __restrict__ dst, int e,
                                              unsigned* __restrict__ binCur,
                                              unsigned* __restrict__ binbuf) {
    __shared__ unsigned scnt[MAXBINS], lbase[MAXBINS], gbase[MAXBINS];
    __shared__ unsigned sbuf[TILE];
    __shared__ unsigned char sbin[TILE];
    int t = threadIdx.x;
    if (t < MAXBINS) scnt[t] = 0u;
    __syncthreads();
    int base = blockIdx.x * TILE;
    unsigned ent[16], rank[16];
    int ebin[16];
#pragma unroll
    for (int i = 0; i < 16; ++i) {
        int j = base + t + i * 512;
        ebin[i] = -1;
        if (j < e) {
            int d = __builtin_nontemporal_load(&dst[j]);
            int s = __builtin_nontemporal_load(&src[j]);
            ent[i] = ((unsigned)s << BSH) | ((unsigned)d & (NPB - 1));
            ebin[i] = d >> BSH;
            rank[i] = atomicAdd(&scnt[ebin[i]], 1u);
        }
    }
    __syncthreads();
    if (t == 0) {
        unsigned run = 0;
        for (int b = 0; b < MAXBINS; ++b) { lbase[b] = run; run += scnt[b]; }
    }
    __syncthreads();
    if (t < MAXBINS && scnt[t] > 0u) gbase[t] = atomicAdd(&binCur[t], scnt[t]);
    __syncthreads();
#pragma unroll
    for (int i = 0; i < 16; ++i)
        if (ebin[i] >= 0) {
            unsigned p = lbase[ebin[i]] + rank[i];
            sbuf[p] = ent[i];
            sbin[p] = (unsigned char)ebin[i];
        }
    __syncthreads();
    int total = e - base; if (total > TILE) total = TILE;
    for (int idx = t; idx < total; idx += 512) {
        int b = sbin[idx];
        __builtin_nontemporal_store(sbuf[idx], &binbuf[gbase[b] + ((unsigned)idx - lbase[b])]);
    }
}

// ---------- pass B: per-bin counting sort by exact dst -> CSR ----------------
__global__ void __launch_bounds__(256) k_binB(const unsigned* __restrict__ binbuf,
                                              const unsigned* __restrict__ binCur,
                                              int n,
                                              unsigned* __restrict__ srcs,
                                              unsigned* __restrict__ off,
                                              unsigned* __restrict__ degc) {
    __shared__ unsigned hist[NPB];
    __shared__ unsigned pref[NPB];
    __shared__ unsigned s1[256];
    int t = threadIdx.x;
    int b = blockIdx.x;
    unsigned base = (unsigned)b * BCAP;
    unsigned end = binCur[b];
    for (int i = t; i < NPB; i += 256) hist[i] = 0u;
    __syncthreads();
    for (unsigned j = base + t; j < end; j += 256)
        atomicAdd(&hist[__builtin_nontemporal_load(&binbuf[j]) & (NPB - 1)], 1u);
    __syncthreads();
    unsigned h0 = hist[2 * t], h1 = hist[2 * t + 1];
    unsigned pair = h0 + h1;
    s1[t] = pair;
    __syncthreads();
    for (int o = 1; o < 256; o <<= 1) {
        unsigned v = (t >= o) ? s1[t - o] : 0u;
        __syncthreads();
        s1[t] += v;
        __syncthreads();
    }
    unsigned exc = s1[t] - pair;
    pref[2 * t] = exc;
    pref[2 * t + 1] = exc + h0;
    __syncthreads();
    int dbase = b << BSH;
    for (int i = t; i < NPB; i += 256) {
        int d = dbase + i;
        if (d < n) { off[d] = base + pref[i]; degc[d] = hist[i]; }
    }
    __syncthreads();
    for (int i = t; i < NPB; i += 256) hist[i] = 0u;  // reuse as cursors
    __syncthreads();
    for (unsigned j = base + t; j < end; j += 256) {
        unsigned v = __builtin_nontemporal_load(&binbuf[j]);
        unsigned dl = v & (NPB - 1);
        unsigned r = atomicAdd(&hist[dl], 1u);
        srcs[base + pref[dl] + r] = v >> BSH;
    }
}

// ---------- GEMM1 via MFMA: t1h[n][16] fp16 = (x@W1)*rsqrt(deg+1) ------------
__global__ void __launch_bounds__(256) k_gemm1(const float* __restrict__ x,
                                               const _Float16* __restrict__ wfrag,
                                               const unsigned* __restrict__ degc,
                                               _Float16* __restrict__ t1h, int n) {
    __shared__ _Float16 xs[4][16 * APITCH];  // 35840 B
    int t = threadIdx.x;
    int lane = t & 63;
    int wv = t >> 6;
    int col = lane & 15;
    int k0 = (lane >> 4) * 8;
    f16x8 bfrag[8];
#pragma unroll
    for (int kc = 0; kc < 8; ++kc)
        bfrag[kc] = *(const f16x8*)&wfrag[((size_t)lane * 8 + kc) * 8];
    int rbase = blockIdx.x * GROWS;
    int nrows = n - rbase; if (nrows > GROWS) nrows = GROWS;
#pragma unroll
    for (int it = 0; it < GROWS * 64 / 256; ++it) {
        int q = t + it * 256;           // float4 index: 64 per row
        int row = q >> 6, c4 = q & 63;
        if (row < nrows) {
            f4v v = __builtin_nontemporal_load(
                &((const f4v*)(x + (size_t)(rbase + row) * F_IN))[c4]);
            f16x4 hv;
            hv[0] = (_Float16)v[0]; hv[1] = (_Float16)v[1];
            hv[2] = (_Float16)v[2]; hv[3] = (_Float16)v[3];
            *(f16x4*)&xs[row >> 4][(row & 15) * APITCH + c4 * 4] = hv;
        }
    }
    __syncthreads();
    f32x4 acc = {0.f, 0.f, 0.f, 0.f};
    const _Float16* tile = xs[wv];
    int arow = lane & 15;
#pragma unroll
    for (int kc = 0; kc < 8; ++kc) {
        f16x8 afrag = *(const f16x8*)&tile[arow * APITCH + kc * 32 + k0];
        acc = __builtin_amdgcn_mfma_f32_16x16x32_f16(afrag, bfrag[kc], acc, 0, 0, 0);
    }
    int r0 = (lane >> 4) * 4;
#pragma unroll
    for (int reg = 0; reg < 4; ++reg) {
        int grow = rbase + wv * 16 + r0 + reg;
        if (grow < n) {
            float v = acc[reg] * rsqrtf((float)(degc[grow] + 1u));
            t1h[(size_t)grow * HID + col] = (_Float16)v;
        }
    }
}

// ---------- conv1 + GEMM2 fused: 8 lanes/dst, uint2 (8B) gathers -------------
__global__ void __launch_bounds__(256) k_agg1g2(const unsigned* __restrict__ srcs,
                                                const unsigned* __restrict__ off,
                                                const unsigned* __restrict__ degc,
                                                const uint2* __restrict__ t1q,  // [n*4] uint2
                                                const float* __restrict__ b1,
                                                const float* __restrict__ W2,
                                                unsigned* __restrict__ t2h, int n) {
    __shared__ float w2s[HID * NCLS];
    __shared__ float b1s[HID];
    int t = threadIdx.x;
    if (t < HID * NCLS) w2s[t] = W2[t];
    if (t < HID) b1s[t] = b1[t];
    __syncthreads();
    int d = blockIdx.x * 32 + (t >> 3);
    if (d >= n) return;            // uniform per 8-lane group
    int q4 = t & 3;                // uint2 index within 32B row (features 4q4..4q4+3)
    int pr = (t >> 2) & 1;         // edge parity
    unsigned p = off[d];
    unsigned c = degc[d];
    float a0 = 0.f, a1 = 0.f, a2 = 0.f, a3 = 0.f;
    union { unsigned u; h2v h; } cv;
    unsigned i = pr;
    for (; i + 6 < c; i += 8) {
        unsigned s0 = srcs[p + i],     s1 = srcs[p + i + 2];
        unsigned s2 = srcs[p + i + 4], s3 = srcs[p + i + 6];
        uint2 w0 = t1q[(size_t)s0 * 4 + q4];
        uint2 w1 = t1q[(size_t)s1 * 4 + q4];
        uint2 w2 = t1q[(size_t)s2 * 4 + q4];
        uint2 w3 = t1q[(size_t)s3 * 4 + q4];
        cv.u = w0.x; a0 += (float)cv.h[0]; a1 += (float)cv.h[1];
        cv.u = w0.y; a2 += (float)cv.h[0]; a3 += (float)cv.h[1];
        cv.u = w1.x; a0 += (float)cv.h[0]; a1 += (float)cv.h[1];
        cv.u = w1.y; a2 += (float)cv.h[0]; a3 += (float)cv.h[1];
        cv.u = w2.x; a0 += (float)cv.h[0]; a1 += (float)cv.h[1];
        cv.u = w2.y; a2 += (float)cv.h[0]; a3 += (float)cv.h[1];
        cv.u = w3.x; a0 += (float)cv.h[0]; a1 += (float)cv.h[1];
        cv.u = w3.y; a2 += (float)cv.h[0]; a3 += (float)cv.h[1];
    }
    for (; i + 2 < c; i += 4) {
        uint2 w0 = t1q[(size_t)srcs[p + i] * 4 + q4];
        uint2 w1 = t1q[(size_t)srcs[p + i + 2] * 4 + q4];
        cv.u = w0.x; a0 += (float)cv.h[0]; a1 += (float)cv.h[1];
        cv.u = w0.y; a2 += (float)cv.h[0]; a3 += (float)cv.h[1];
        cv.u = w1.x; a0 += (float)cv.h[0]; a1 += (float)cv.h[1];
        cv.u = w1.y; a2 += (float)cv.h[0]; a3 += (float)cv.h[1];
    }
    if (i < c) {
        uint2 w = t1q[(size_t)srcs[p + i] * 4 + q4];
        cv.u = w.x; a0 += (float)cv.h[0]; a1 += (float)cv.h[1];
        cv.u = w.y; a2 += (float)cv.h[0]; a3 += (float)cv.h[1];
    }
    // merge edge-parity halves (all 8 lanes alive)
    a0 += __shfl_xor(a0, 4, 64);
    a1 += __shfl_xor(a1, 4, 64);
    a2 += __shfl_xor(a2, 4, 64);
    a3 += __shfl_xor(a3, 4, 64);
    // self loop (both halves compute identically)
    uint2 sl = t1q[(size_t)d * 4 + q4];
    cv.u = sl.x; a0 += (float)cv.h[0]; a1 += (float)cv.h[1];
    cv.u = sl.y; a2 += (float)cv.h[0]; a3 += (float)cv.h[1];
    float di = rsqrtf((float)(c + 1u));
    float h0 = fmaxf(di * a0 + b1s[4 * q4 + 0], 0.f);
    float h1 = fmaxf(di * a1 + b1s[4 * q4 + 1], 0.f);
    float h2 = fmaxf(di * a2 + b1s[4 * q4 + 2], 0.f);
    float h3 = fmaxf(di * a3 + b1s[4 * q4 + 3], 0.f);
    // GEMM2 partials: this lane covers k = 4q4..4q4+3
    float o[NCLS];
#pragma unroll
    for (int cc = 0; cc < NCLS; ++cc)
        o[cc] = h0 * w2s[(4 * q4 + 0) * NCLS + cc] + h1 * w2s[(4 * q4 + 1) * NCLS + cc]
              + h2 * w2s[(4 * q4 + 2) * NCLS + cc] + h3 * w2s[(4 * q4 + 3) * NCLS + cc];
    // butterfly over the 4-lane quad (both parity halves redundantly)
#pragma unroll
    for (int m = 1; m < 4; m <<= 1)
#pragma unroll
        for (int cc = 0; cc < NCLS; ++cc)
            o[cc] += __shfl_xor(o[cc], m, 64);
    if (pr == 0) {
        union { unsigned u; h2v h; } pk;
        pk.h[0] = (_Float16)(o[2 * q4] * di);
        pk.h[1] = (_Float16)(o[2 * q4 + 1] * di);
        t2h[(size_t)d * 4 + q4] = pk.u;
    }
}

// ---------- conv2: 4 lanes/dst, uint2 gathers, fused mean-pool ---------------
__global__ void __launch_bounds__(256) k_agg2pool(const unsigned* __restrict__ srcs,
                                                  const unsigned* __restrict__ off,
                                                  const unsigned* __restrict__ degc,
                                                  const uint2* __restrict__ t2q,  // [n*2] uint2
                                                  const float* __restrict__ b2,
                                                  const int* __restrict__ batch,
                                                  float* __restrict__ out,
                                                  float* __restrict__ cg, int n) {
    __shared__ float wacc[WIN * NCLS];
    __shared__ float wcnt[WIN];
    __shared__ int gb_s;
    int t = threadIdx.x;
    int bbase = blockIdx.x * 64;
    if (t < WIN * NCLS) wacc[t] = 0.f;
    if (t < WIN) wcnt[t] = 0.f;
    if (t == 0) gb_s = batch[bbase < n ? bbase : (n - 1)];
    __syncthreads();
    int d = bbase + (t >> 2);
    int q2 = t & 1;                // uint2 index (features 4q2..4q2+3)
    int pr = (t >> 1) & 1;         // edge parity
    if (d < n) {
        unsigned p = off[d];
        unsigned c = degc[d];
        float a0 = 0.f, a1 = 0.f, a2 = 0.f, a3 = 0.f;
        union { unsigned u; h2v h; } cv;
        unsigned i = pr;
        for (; i + 6 < c; i += 8) {
            uint2 w0 = t2q[(size_t)srcs[p + i] * 2 + q2];
            uint2 w1 = t2q[(size_t)srcs[p + i + 2] * 2 + q2];
            uint2 w2 = t2q[(size_t)srcs[p + i + 4] * 2 + q2];
            uint2 w3 = t2q[(size_t)srcs[p + i + 6] * 2 + q2];
            cv.u = w0.x; a0 += (float)cv.h[0]; a1 += (float)cv.h[1];
            cv.u = w0.y; a2 += (float)cv.h[0]; a3 += (float)cv.h[1];
            cv.u = w1.x; a0 += (float)cv.h[0]; a1 += (float)cv.h[1];
            cv.u = w1.y; a2 += (float)cv.h[0]; a3 += (float)cv.h[1];
            cv.u = w2.x; a0 += (float)cv.h[0]; a1 += (float)cv.h[1];
            cv.u = w2.y; a2 += (float)cv.h[0]; a3 += (float)cv.h[1];
            cv.u = w3.x; a0 += (float)cv.h[0]; a1 += (float)cv.h[1];
            cv.u = w3.y; a2 += (float)cv.h[0]; a3 += (float)cv.h[1];
        }
        for (; i + 2 < c; i += 4) {
            uint2 w0 = t2q[(size_t)srcs[p + i] * 2 + q2];
            uint2 w1 = t2q[(size_t)srcs[p + i + 2] * 2 + q2];
            cv.u = w0.x; a0 += (float)cv.h[0]; a1 += (float)cv.h[1];
            cv.u = w0.y; a2 += (float)cv.h[0]; a3 += (float)cv.h[1];
            cv.u = w1.x; a0 += (float)cv.h[0]; a1 += (float)cv.h[1];
            cv.u = w1.y; a2 += (float)cv.h[0]; a3 += (float)cv.h[1];
        }
        if (i < c) {
            uint2 w = t2q[(size_t)srcs[p + i] * 2 + q2];
            cv.u = w.x; a0 += (float)cv.h[0]; a1 += (float)cv.h[1];
            cv.u = w.y; a2 += (float)cv.h[0]; a3 += (float)cv.h[1];
        }
        a0 += __shfl_xor(a0, 2, 64);
        a1 += __shfl_xor(a1, 2, 64);
        a2 += __shfl_xor(a2, 2, 64);
        a3 += __shfl_xor(a3, 2, 64);
        if (pr == 0) {
            uint2 sl = t2q[(size_t)d * 2 + q2];  // self loop
            cv.u = sl.x; a0 += (float)cv.h[0]; a1 += (float)cv.h[1];
            cv.u = sl.y; a2 += (float)cv.h[0]; a3 += (float)cv.h[1];
            float di = rsqrtf((float)(c + 1u));
            int f0 = 4 * q2;
            float v0 = di * a0 + b2[f0 + 0];
            float v1 = di * a1 + b2[f0 + 1];
            float v2 = di * a2 + b2[f0 + 2];
            float v3 = di * a3 + b2[f0 + 3];
            int g = batch[d];
            int gi = g - gb_s;
            if (gi < WIN) {
                atomicAdd(&wacc[gi * NCLS + f0 + 0], v0);
                atomicAdd(&wacc[gi * NCLS + f0 + 1], v1);
                atomicAdd(&wacc[gi * NCLS + f0 + 2], v2);
                atomicAdd(&wacc[gi * NCLS + f0 + 3], v3);
                if ((t & 3) == 0) atomicAdd(&wcnt[gi], 1.f);
            } else {
                atomicAdd(&out[(size_t)g * NCLS + f0 + 0], v0);
                atomicAdd(&out[(size_t)g * NCLS + f0 + 1], v1);
                atomicAdd(&out[(size_t)g * NCLS + f0 + 2], v2);
                atomicAdd(&out[(size_t)g * NCLS + f0 + 3], v3);
                if ((t & 3) == 0) atomicAdd(&cg[g], 1.f);
            }
        }
    }
    __syncthreads();
    if (t < WIN * NCLS && wcnt[t >> 3] > 0.f)
        atomicAdd(&out[(size_t)(gb_s + (t >> 3)) * NCLS + (t & 7)], wacc[t]);
    if (t < WIN && wcnt[t] > 0.f) atomicAdd(&cg[gb_s + t], wcnt[t]);
}

__global__ void k_div(float* __restrict__ out, const float* __restrict__ cg, int total) {
    int i = blockIdx.x * blockDim.x + threadIdx.x;
    if (i < total) out[i] /= fmaxf(cg[i / NCLS], 1.0f);
}

extern "C" void kernel_launch(void* const* d_in, const int* in_sizes, int n_in,
                              void* d_out, int out_size, void* d_ws, size_t ws_size,
                              hipStream_t stream) {
    const float* x = (const float*)d_in[0];
    const int* ei = (const int*)d_in[1];
    const int* batch = (const int*)d_in[2];
    const float* W1 = (const float*)d_in[4];
    const float* b1 = (const float*)d_in[5];
    const float* W2 = (const float*)d_in[6];
    const float* b2 = (const float*)d_in[7];

    int n = in_sizes[0] / F_IN;
    int e = in_sizes[1] / 2;
    int g = out_size / NCLS;
    const int* src = ei;
    const int* dst = ei + e;
    int nbins = (n + NPB - 1) >> BSH;  // 196 for n=100000

    char* w = (char*)d_ws;
    unsigned* binCur = (unsigned*)w; w += (size_t)MAXBINS * 4;
    unsigned* degc   = (unsigned*)w; w += (size_t)n * 4;
    unsigned* off    = (unsigned*)w; w += (size_t)n * 4;
    unsigned* t1h    = (unsigned*)w; w += (size_t)n * 8 * 4;   // fp16 pairs, 3.2 MB
    unsigned* t2h    = (unsigned*)w; w += (size_t)n * 4 * 4;   // fp16 pairs, 1.6 MB
    _Float16* wfrag  = (_Float16*)w; w += (size_t)64 * 8 * 8 * 2;  // 8 KB
    float* cg        = (float*)w;    w += (size_t)g * 4;
    w = (char*)(((size_t)w + 255) & ~(size_t)255);
    unsigned* binbuf = (unsigned*)w; w += (size_t)nbins * BCAP * 4;  // 14.5 MB
    unsigned* srcs   = (unsigned*)w; w += (size_t)nbins * BCAP * 4;  // 14.5 MB

    k_init<<<1, 256, 0, stream>>>(binCur, nbins, W1, wfrag, cg, g, (float*)d_out, out_size);
    k_binA<<<(e + TILE - 1) / TILE, 512, 0, stream>>>(src, dst, e, binCur, binbuf);
    k_binB<<<nbins, 256, 0, stream>>>(binbuf, binCur, n, srcs, off, degc);
    k_gemm1<<<(n + GROWS - 1) / GROWS, 256, 0, stream>>>(x, wfrag, degc, (_Float16*)t1h, n);
    k_agg1g2<<<(n + 31) / 32, 256, 0, stream>>>(srcs, off, degc, (const uint2*)t1h,
                                                b1, W2, t2h, n);
    k_agg2pool<<<(n + 63) / 64, 256, 0, stream>>>(srcs, off, degc, (const uint2*)t2h,
                                                  b2, batch, (float*)d_out, cg, n);
    k_div<<<(out_size + 255) / 256, 256, 0, stream>>>((float*)d_out, cg, out_size);
}